// Round 6
// baseline (1135.293 us; speedup 1.0000x reference)
//
#include <hip/hip_runtime.h>
#include <hip/hip_bf16.h>

#define NB 64
#define NS 512
#define NV 1000
#define NF 64
#define NH 256

typedef short bf16x8 __attribute__((ext_vector_type(8)));
typedef float f32x4 __attribute__((ext_vector_type(4)));

__device__ __forceinline__ float bf2f(unsigned int u16bits){
    union { unsigned int i; float f; } v;
    v.i = (u16bits & 0xffffu) << 16;
    return v.f;
}

__device__ __forceinline__ unsigned pack2bf(float a, float b){
    union { float f; unsigned u; } x, y; x.f = a; y.f = b;
    unsigned lo = (x.u + 0x7FFFu + ((x.u >> 16) & 1u)) >> 16;
    unsigned hi = (y.u + 0x7FFFu + ((y.u >> 16) & 1u)) >> 16;
    return (lo & 0xFFFFu) | (hi << 16);
}

__device__ __forceinline__ float tanh_fast(float x){
    float e = __builtin_amdgcn_exp2f(x * 2.8853900817779268f);
    return 1.f - 2.f * __builtin_amdgcn_rcpf(e + 1.f);
}

__device__ __forceinline__ bool detect_f32(const void* probe){
    const unsigned short* p = (const unsigned short*)probe;
    bool bad = false; float mx = 0.f;
#pragma unroll
    for (int j = 0; j < 64; ++j){
        float v = fabsf(bf2f(p[j]));
        bad = bad || !(v == v);
        mx = fmaxf(mx, v);
    }
    return bad || (mx > 100.f);
}

// ---------------------------------------------------------------------------
// K0: canonicalize all 11 float inputs into bf16 — ONE launch.
// ---------------------------------------------------------------------------
struct ConvArgs { const void* src[11]; __hip_bfloat16* dst[11]; int n[11]; };

__global__ void k_conv_all(ConvArgs a, const void* __restrict__ probe){
    const int seg = blockIdx.y;
    const int n = a.n[seg];
    int i = blockIdx.x * 256 + threadIdx.x;
    if (i >= n) return;
    const bool f32in = detect_f32(probe);
    const int stride = gridDim.x * 256;
    __hip_bfloat16* dst = a.dst[seg];
    if (f32in){
        const float* s = (const float*)a.src[seg];
        for (; i < n; i += stride) dst[i] = __float2bfloat16(s[i]);
    } else {
        const unsigned short* s = (const unsigned short*)a.src[seg];
        for (; i < n; i += stride) dst[i] = __float2bfloat16(bf2f(s[i]));
    }
}

// ---------------------------------------------------------------------------
// K1: pre0[v][h] = dot(features[v,:], W_ih0[h,:]) + b_ih0[h] + b_hh0[h]  (f32)
// ---------------------------------------------------------------------------
__global__ void k_pre0(const __hip_bfloat16* __restrict__ feats,
                       const __hip_bfloat16* __restrict__ Wih,
                       const __hip_bfloat16* __restrict__ bih,
                       const __hip_bfloat16* __restrict__ bhh,
                       float* __restrict__ pre0){
    const int v = blockIdx.x, h = threadIdx.x;
    __shared__ __align__(16) float fsh[NF];
    if (h < NF) fsh[h] = __bfloat162float(feats[v*NF + h]);
    __syncthreads();
    const uint4* wr = reinterpret_cast<const uint4*>(Wih + h*NF);
    float acc = __bfloat162float(bih[h]) + __bfloat162float(bhh[h]);
#pragma unroll
    for (int j = 0; j < 8; ++j){
        uint4 q = wr[j];
        const float* hf = &fsh[j*8];
        acc += hf[0]*bf2f(q.x) + hf[1]*bf2f(q.x>>16)
             + hf[2]*bf2f(q.y) + hf[3]*bf2f(q.y>>16)
             + hf[4]*bf2f(q.z) + hf[5]*bf2f(q.z>>16)
             + hf[6]*bf2f(q.w) + hf[7]*bf2f(q.w>>16);
    }
    pre0[v*NH + h] = acc;
}

// ---------------------------------------------------------------------------
// K2/K4: MFMA RNN recurrence. Grid = 4 WGs x 256 threads (4 waves), 16 batch
// rows per WG, 64 output cols per wave. Per step: D = Whh @ H^T:
//   A = Whh frags (128 VGPR/thread, loaded once)  B = H frags from LDS.
// LDS H layout [k8][row]*16B: reads/writes both conflict-free (contiguous).
// Barrier = s_waitcnt lgkmcnt(0) + s_barrier ONLY — no vmcnt drain, so hout
// stores and xp prefetch loads pipeline across steps (depth-2 prefetch).
// ---------------------------------------------------------------------------
#define BAR() do { asm volatile("s_waitcnt lgkmcnt(0)" ::: "memory");  \
                   __builtin_amdgcn_s_barrier();                        \
                   asm volatile("" ::: "memory"); } while (0)

#define RNN_STEP(RBUF, WBUF, XQ, BQ, S)                                          \
  do {                                                                           \
    const int sn = ((S) + 2 < NS) ? (S) + 2 : NS - 1;                            \
    float4 nx[4]; ushort4 nb[4];                                                 \
    if (LAYER == 0){                                                             \
        int idx = bsh[lr*NS + sn];                                               \
        _Pragma("unroll") for (int nt = 0; nt < 4; ++nt)                         \
            nx[nt] = *reinterpret_cast<const float4*>(                           \
                xf + (size_t)idx*NH + c0 + nt*16 + kq*4);                        \
    } else {                                                                     \
        const unsigned short* bse = xb + ((size_t)(b0+lr)*NS + sn)*NH;           \
        _Pragma("unroll") for (int nt = 0; nt < 4; ++nt)                         \
            nb[nt] = *reinterpret_cast<const ushort4*>(bse + c0 + nt*16 + kq*4); \
    }                                                                            \
    bf16x8 hf[8];                                                                \
    _Pragma("unroll") for (int ks = 0; ks < 8; ++ks)                             \
        hf[ks] = *reinterpret_cast<const bf16x8*>((const char*)(RBUF) + roff[ks]);\
    f32x4 acc[4] = {};                                                           \
    _Pragma("unroll") for (int ks = 0; ks < 8; ++ks){                            \
        _Pragma("unroll") for (int nt = 0; nt < 4; ++nt)                         \
            acc[nt] = __builtin_amdgcn_mfma_f32_16x16x32_bf16(                   \
                wf[nt][ks], hf[ks], acc[nt], 0, 0, 0);                           \
    }                                                                            \
    _Pragma("unroll") for (int nt = 0; nt < 4; ++nt){                            \
        float t[4];                                                              \
        _Pragma("unroll") for (int r = 0; r < 4; ++r){                           \
            float x = (LAYER == 0) ? ((const float*)&XQ[nt])[r]                  \
                                   : bf2f(((const unsigned short*)&BQ[nt])[r]);  \
            t[r] = tanh_fast(acc[nt][r] + x);                                    \
        }                                                                        \
        uint2 p = { pack2bf(t[0], t[1]), pack2bf(t[2], t[3]) };                  \
        *reinterpret_cast<uint2*>((char*)(WBUF) + woff[nt]) = p;                 \
        *reinterpret_cast<uint2*>(hob + (size_t)(S)*NH + nt*16 + kq*4) = p;      \
    }                                                                            \
    _Pragma("unroll") for (int nt = 0; nt < 4; ++nt){ XQ[nt] = nx[nt]; BQ[nt] = nb[nt]; } \
  } while (0)

template<int LAYER>
__global__ __launch_bounds__(256, 1) void k_rnn(const int* __restrict__ batch,
                                                const void* __restrict__ xpv,
                                                const __hip_bfloat16* __restrict__ Whh,
                                                __hip_bfloat16* __restrict__ hout){
    const int l  = threadIdx.x & 63;
    const int w  = threadIdx.x >> 6;   // 0..3
    const int b0 = blockIdx.x * 16;
    const int lr = l & 15;             // batch row (B/D) and Whh out-col (A)
    const int kq = l >> 4;             // 0..3 k-quarter
    const int c0 = w * 64;             // wave's output-col base

    // A-frags: Whh[c0+nt*16+lr][ks*32+kq*8 .. +8]
    bf16x8 wf[4][8];
#pragma unroll
    for (int nt = 0; nt < 4; ++nt)
#pragma unroll
        for (int ks = 0; ks < 8; ++ks)
            wf[nt][ks] = *reinterpret_cast<const bf16x8*>(
                Whh + (size_t)(c0 + nt*16 + lr)*NH + ks*32 + kq*8);

    __shared__ __align__(16) unsigned short h0[4096], h1[4096]; // [k8][row] 16B chunks
    __shared__ int bsh[16*NS];                                   // batch rows (layer 0)

    *reinterpret_cast<uint4*>(&h0[threadIdx.x*8])        = uint4{0,0,0,0};
    *reinterpret_cast<uint4*>(&h0[2048 + threadIdx.x*8]) = uint4{0,0,0,0};
    if (LAYER == 0){
        const int4* bsrc = reinterpret_cast<const int4*>(batch + (size_t)b0*NS);
        int4* bdst = reinterpret_cast<int4*>(bsh);
#pragma unroll
        for (int i = 0; i < 8; ++i)
            bdst[threadIdx.x + i*256] = bsrc[threadIdx.x + i*256];
    }

    const float*          xf = (const float*)xpv;
    const unsigned short* xb = (const unsigned short*)xpv;

    int roff[8];
#pragma unroll
    for (int ks = 0; ks < 8; ++ks)
        roff[ks] = ks*1024 + kq*256 + lr*16;
    int woff[4];
#pragma unroll
    for (int nt = 0; nt < 4; ++nt){
        int c = c0 + nt*16 + kq*4;
        woff[nt] = (c >> 3)*256 + lr*16 + (c & 7)*2;
    }
    __hip_bfloat16* hob = hout + ((size_t)(b0+lr)*NS)*NH + c0;

    __syncthreads();   // bsh + h0 visible (once; vmcnt drain harmless here)

    // depth-2 prefetch: slots A (even steps) and B (odd steps)
    float4 xqA[4], xqB[4]; ushort4 bqA[4], bqB[4];
    if (LAYER == 0){
        int i0 = bsh[lr*NS + 0], i1 = bsh[lr*NS + 1];
#pragma unroll
        for (int nt = 0; nt < 4; ++nt){
            xqA[nt] = *reinterpret_cast<const float4*>(xf + (size_t)i0*NH + c0 + nt*16 + kq*4);
            xqB[nt] = *reinterpret_cast<const float4*>(xf + (size_t)i1*NH + c0 + nt*16 + kq*4);
        }
    } else {
        const unsigned short* s0 = xb + ((size_t)(b0+lr)*NS + 0)*NH;
        const unsigned short* s1 = xb + ((size_t)(b0+lr)*NS + 1)*NH;
#pragma unroll
        for (int nt = 0; nt < 4; ++nt){
            bqA[nt] = *reinterpret_cast<const ushort4*>(s0 + c0 + nt*16 + kq*4);
            bqB[nt] = *reinterpret_cast<const ushort4*>(s1 + c0 + nt*16 + kq*4);
        }
    }

    for (int s = 0; s < NS; s += 2){
        RNN_STEP(h0, h1, xqA, bqA, s);      // read h0, write h1
        BAR();
        RNN_STEP(h1, h0, xqB, bqB, s + 1);  // read h1, write h0
        BAR();
    }
}

// ---------------------------------------------------------------------------
// K3/K5: C[M,N] = A[M,256] @ W[N,256]^T (+bias1+bias2), MFMA 16x16x32 bf16.
// ---------------------------------------------------------------------------
template<int N>
__global__ void k_gemm(const __hip_bfloat16* __restrict__ A,
                       const __hip_bfloat16* __restrict__ W,
                       const __hip_bfloat16* __restrict__ bias1,
                       const __hip_bfloat16* __restrict__ bias2,
                       void* __restrict__ Cout, int ldc,
                       const void* __restrict__ probe){
    const bool f32out = probe ? detect_f32(probe) : false;
    const int m0 = blockIdx.x * 64;
    const int n0 = blockIdx.y * 64;
    const int wv = threadIdx.x >> 6;
    const int l  = threadIdx.x & 63;
    const int mrow  = m0 + wv*16 + (l & 15);
    const int kbase = (l >> 4) * 8;

    f32x4 acc[4] = {};
#pragma unroll
    for (int ks = 0; ks < 8; ++ks){
        bf16x8 af = *reinterpret_cast<const bf16x8*>(A + (size_t)mrow*NH + ks*32 + kbase);
#pragma unroll
        for (int nt = 0; nt < 4; ++nt){
            int ncol = n0 + nt*16 + (l & 15);
            int nc = (ncol < N) ? ncol : (N-1);
            bf16x8 bfr = *reinterpret_cast<const bf16x8*>(W + (size_t)nc*NH + ks*32 + kbase);
            acc[nt] = __builtin_amdgcn_mfma_f32_16x16x32_bf16(af, bfr, acc[nt], 0, 0, 0);
        }
    }
#pragma unroll
    for (int nt = 0; nt < 4; ++nt){
        int ncol = n0 + nt*16 + (l & 15);
        if (ncol >= N) continue;
        float bsum = __bfloat162float(bias1[ncol]) + (bias2 ? __bfloat162float(bias2[ncol]) : 0.f);
#pragma unroll
        for (int r = 0; r < 4; ++r){
            int row = m0 + wv*16 + (l>>4)*4 + r;
            float val = acc[nt][r] + bsum;
            if (f32out) ((float*)Cout)[(size_t)row*ldc + ncol] = val;
            else        ((__hip_bfloat16*)Cout)[(size_t)row*ldc + ncol] = __float2bfloat16(val);
        }
    }
}

// ---------------------------------------------------------------------------
extern "C" void kernel_launch(void* const* d_in, const int* in_sizes, int n_in,
                              void* d_out, int out_size, void* d_ws, size_t ws_size,
                              hipStream_t stream){
    const int* batch = (const int*)d_in[0];
    const void* probe = d_in[3];  // raw W_hh0 for dtype detection

    char* ws = (char*)d_ws;
    size_t off = 0;
    auto give = [&](size_t bytes)->char*{
        char* p = ws + off; off = (off + bytes + 511) & ~(size_t)511; return p;
    };
    __hip_bfloat16* cFeats = (__hip_bfloat16*)give(2*NV*NF);
    __hip_bfloat16* cWih0  = (__hip_bfloat16*)give(2*NH*NF);
    __hip_bfloat16* cWhh0  = (__hip_bfloat16*)give(2*NH*NH);
    __hip_bfloat16* cBih0  = (__hip_bfloat16*)give(2*NH);
    __hip_bfloat16* cBhh0  = (__hip_bfloat16*)give(2*NH);
    __hip_bfloat16* cWih1  = (__hip_bfloat16*)give(2*NH*NH);
    __hip_bfloat16* cWhh1  = (__hip_bfloat16*)give(2*NH*NH);
    __hip_bfloat16* cBih1  = (__hip_bfloat16*)give(2*NH);
    __hip_bfloat16* cBhh1  = (__hip_bfloat16*)give(2*NH);
    __hip_bfloat16* cWout  = (__hip_bfloat16*)give(2*NV*NH);
    __hip_bfloat16* cBout  = (__hip_bfloat16*)give(2*NV);
    float*          pre0   = (float*)give(4*NV*NH);
    __hip_bfloat16* hbuf   = (__hip_bfloat16*)give(2*(size_t)NB*NS*NH);
    __hip_bfloat16* xp1    = (__hip_bfloat16*)give(2*(size_t)NB*NS*NH);

    ConvArgs ca;
    const void* srcs[11] = { d_in[1], d_in[2], d_in[3], d_in[4], d_in[5], d_in[6],
                             d_in[7], d_in[8], d_in[9], d_in[10], d_in[11] };
    __hip_bfloat16* dsts[11] = { cFeats, cWih0, cWhh0, cBih0, cBhh0, cWih1,
                                 cWhh1, cBih1, cBhh1, cWout, cBout };
    int ns[11] = { NV*NF, NH*NF, NH*NH, NH, NH, NH*NH, NH*NH, NH, NH, NV*NH, NV };
    for (int i = 0; i < 11; ++i){ ca.src[i] = srcs[i]; ca.dst[i] = dsts[i]; ca.n[i] = ns[i]; }
    k_conv_all<<<dim3(500, 11), dim3(256), 0, stream>>>(ca, probe);

    k_pre0<<<dim3(NV), dim3(256), 0, stream>>>(cFeats, cWih0, cBih0, cBhh0, pre0);
    k_rnn<0><<<dim3(NB/16), dim3(256), 0, stream>>>(batch, pre0, cWhh0, hbuf);
    k_gemm<NH><<<dim3((NB*NS)/64, NH/64), dim3(256), 0, stream>>>(
        hbuf, cWih1, cBih1, cBhh1, xp1, NH, nullptr);
    k_rnn<1><<<dim3(NB/16), dim3(256), 0, stream>>>(batch, xp1, cWhh1, hbuf);
    k_gemm<NV><<<dim3((NB*NS)/64, 16), dim3(256), 0, stream>>>(
        hbuf, cWout, cBout, nullptr, d_out, NV, probe);
}

// Round 7
// 1127.933 us; speedup vs baseline: 1.0065x; 1.0065x over previous
//
#include <hip/hip_runtime.h>
#include <hip/hip_bf16.h>

#define NB 64
#define NS 512
#define NV 1000
#define NF 64
#define NH 256

typedef short bf16x8 __attribute__((ext_vector_type(8)));
typedef float f32x4 __attribute__((ext_vector_type(4)));

__device__ __forceinline__ float bf2f(unsigned int u16bits){
    union { unsigned int i; float f; } v;
    v.i = (u16bits & 0xffffu) << 16;
    return v.f;
}

__device__ __forceinline__ unsigned pack2bf(float a, float b){
    union { float f; unsigned u; } x, y; x.f = a; y.f = b;
    unsigned lo = (x.u + 0x7FFFu + ((x.u >> 16) & 1u)) >> 16;
    unsigned hi = (y.u + 0x7FFFu + ((y.u >> 16) & 1u)) >> 16;
    return (lo & 0xFFFFu) | (hi << 16);
}

__device__ __forceinline__ float tanh_fast(float x){
    float e = __builtin_amdgcn_exp2f(x * 2.8853900817779268f);
    return 1.f - 2.f * __builtin_amdgcn_rcpf(e + 1.f);
}

__device__ __forceinline__ bool detect_f32(const void* probe){
    const unsigned short* p = (const unsigned short*)probe;
    bool bad = false; float mx = 0.f;
#pragma unroll
    for (int j = 0; j < 64; ++j){
        float v = fabsf(bf2f(p[j]));
        bad = bad || !(v == v);
        mx = fmaxf(mx, v);
    }
    return bad || (mx > 100.f);
}

// ---------------------------------------------------------------------------
// K0: canonicalize all 11 float inputs into bf16 — ONE launch.
// ---------------------------------------------------------------------------
struct ConvArgs { const void* src[11]; __hip_bfloat16* dst[11]; int n[11]; };

__global__ void k_conv_all(ConvArgs a, const void* __restrict__ probe){
    const int seg = blockIdx.y;
    const int n = a.n[seg];
    int i = blockIdx.x * 256 + threadIdx.x;
    if (i >= n) return;
    const bool f32in = detect_f32(probe);
    const int stride = gridDim.x * 256;
    __hip_bfloat16* dst = a.dst[seg];
    if (f32in){
        const float* s = (const float*)a.src[seg];
        for (; i < n; i += stride) dst[i] = __float2bfloat16(s[i]);
    } else {
        const unsigned short* s = (const unsigned short*)a.src[seg];
        for (; i < n; i += stride) dst[i] = __float2bfloat16(bf2f(s[i]));
    }
}

// ---------------------------------------------------------------------------
// K1: pre0[v][h] = dot(features[v,:], W_ih0[h,:]) + b_ih0[h] + b_hh0[h]  (f32)
// ---------------------------------------------------------------------------
__global__ void k_pre0(const __hip_bfloat16* __restrict__ feats,
                       const __hip_bfloat16* __restrict__ Wih,
                       const __hip_bfloat16* __restrict__ bih,
                       const __hip_bfloat16* __restrict__ bhh,
                       float* __restrict__ pre0){
    const int v = blockIdx.x, h = threadIdx.x;
    __shared__ __align__(16) float fsh[NF];
    if (h < NF) fsh[h] = __bfloat162float(feats[v*NF + h]);
    __syncthreads();
    const uint4* wr = reinterpret_cast<const uint4*>(Wih + h*NF);
    float acc = __bfloat162float(bih[h]) + __bfloat162float(bhh[h]);
#pragma unroll
    for (int j = 0; j < 8; ++j){
        uint4 q = wr[j];
        const float* hf = &fsh[j*8];
        acc += hf[0]*bf2f(q.x) + hf[1]*bf2f(q.x>>16)
             + hf[2]*bf2f(q.y) + hf[3]*bf2f(q.y>>16)
             + hf[4]*bf2f(q.z) + hf[5]*bf2f(q.z>>16)
             + hf[6]*bf2f(q.w) + hf[7]*bf2f(q.w>>16);
    }
    pre0[v*NH + h] = acc;
}

// ---------------------------------------------------------------------------
// K2/K4: MFMA RNN recurrence. Grid = 4 WGs x 256 threads (4 waves), 16 batch
// rows per WG, 64 output cols per wave. Per step: D = Whh @ H^T:
//   A = Whh frags — 128 VGPR/thread, loaded ONCE and PINNED via asm so the
//       compiler cannot sink/rematerialize the loads into the loop (round-6
//       pathology: VGPR_Count=104 + FETCH 8.4MB = weights re-fetched per step).
//   B = H frags from LDS, [k8][row]*16B layout, conflict-free both sides.
// Barrier = s_waitcnt lgkmcnt(0) + s_barrier ONLY — global stores/prefetch
// loads pipeline across steps (depth-2 prefetch).
// ---------------------------------------------------------------------------
#define BAR() do { asm volatile("s_waitcnt lgkmcnt(0)" ::: "memory");  \
                   __builtin_amdgcn_s_barrier();                        \
                   asm volatile("" ::: "memory"); } while (0)

#define RNN_STEP(RBUF, WBUF, XQ, BQ, S)                                          \
  do {                                                                           \
    const int sn = ((S) + 2 < NS) ? (S) + 2 : NS - 1;                            \
    float4 nx[4]; ushort4 nb[4];                                                 \
    if (LAYER == 0){                                                             \
        int idx = bsh[lr*NS + sn];                                               \
        _Pragma("unroll") for (int nt = 0; nt < 4; ++nt)                         \
            nx[nt] = *reinterpret_cast<const float4*>(                           \
                xf + (size_t)idx*NH + c0 + nt*16 + kq*4);                        \
    } else {                                                                     \
        const unsigned short* bse = xb + ((size_t)(b0+lr)*NS + sn)*NH;           \
        _Pragma("unroll") for (int nt = 0; nt < 4; ++nt)                         \
            nb[nt] = *reinterpret_cast<const ushort4*>(bse + c0 + nt*16 + kq*4); \
    }                                                                            \
    bf16x8 hf[8];                                                                \
    _Pragma("unroll") for (int ks = 0; ks < 8; ++ks)                             \
        hf[ks] = *reinterpret_cast<const bf16x8*>((const char*)(RBUF) + roff[ks]);\
    f32x4 acc[4] = {};                                                           \
    _Pragma("unroll") for (int ks = 0; ks < 8; ++ks){                            \
        _Pragma("unroll") for (int nt = 0; nt < 4; ++nt)                         \
            acc[nt] = __builtin_amdgcn_mfma_f32_16x16x32_bf16(                   \
                wf[nt][ks], hf[ks], acc[nt], 0, 0, 0);                           \
    }                                                                            \
    _Pragma("unroll") for (int nt = 0; nt < 4; ++nt){                            \
        float t[4];                                                              \
        _Pragma("unroll") for (int r = 0; r < 4; ++r){                           \
            float x = (LAYER == 0) ? ((const float*)&XQ[nt])[r]                  \
                                   : bf2f(((const unsigned short*)&BQ[nt])[r]);  \
            t[r] = tanh_fast(acc[nt][r] + x);                                    \
        }                                                                        \
        uint2 p = { pack2bf(t[0], t[1]), pack2bf(t[2], t[3]) };                  \
        *reinterpret_cast<uint2*>((char*)(WBUF) + woff[nt]) = p;                 \
        *reinterpret_cast<uint2*>(hob + (size_t)(S)*NH + nt*16 + kq*4) = p;      \
    }                                                                            \
    _Pragma("unroll") for (int nt = 0; nt < 4; ++nt){ XQ[nt] = nx[nt]; BQ[nt] = nb[nt]; } \
  } while (0)

template<int LAYER>
__global__ __launch_bounds__(256, 1) void k_rnn(const int* __restrict__ batch,
                                                const void* __restrict__ xpv,
                                                const __hip_bfloat16* __restrict__ Whh,
                                                __hip_bfloat16* __restrict__ hout){
    const int l  = threadIdx.x & 63;
    const int w  = threadIdx.x >> 6;   // 0..3
    const int b0 = blockIdx.x * 16;
    const int lr = l & 15;             // batch row (B/D) and Whh out-col (A)
    const int kq = l >> 4;             // 0..3 k-quarter
    const int c0 = w * 64;             // wave's output-col base

    // A-frags: Whh[c0+nt*16+lr][ks*32+kq*8 .. +8] — loaded once, PINNED.
    bf16x8 wf[4][8];
#pragma unroll
    for (int nt = 0; nt < 4; ++nt)
#pragma unroll
        for (int ks = 0; ks < 8; ++ks){
            wf[nt][ks] = *reinterpret_cast<const bf16x8*>(
                Whh + (size_t)(c0 + nt*16 + lr)*NH + ks*32 + kq*8);
            asm volatile("" : "+v"(wf[nt][ks]));   // forbid sink/remat: keep resident
        }

    __shared__ __align__(16) unsigned short h0[4096], h1[4096]; // [k8][row] 16B chunks
    __shared__ int bsh[16*NS];                                   // batch rows (layer 0)

    *reinterpret_cast<uint4*>(&h0[threadIdx.x*8])        = uint4{0,0,0,0};
    *reinterpret_cast<uint4*>(&h0[2048 + threadIdx.x*8]) = uint4{0,0,0,0};
    if (LAYER == 0){
        const int4* bsrc = reinterpret_cast<const int4*>(batch + (size_t)b0*NS);
        int4* bdst = reinterpret_cast<int4*>(bsh);
#pragma unroll
        for (int i = 0; i < 8; ++i)
            bdst[threadIdx.x + i*256] = bsrc[threadIdx.x + i*256];
    }

    const float*          xf = (const float*)xpv;
    const unsigned short* xb = (const unsigned short*)xpv;

    int roff[8];
#pragma unroll
    for (int ks = 0; ks < 8; ++ks)
        roff[ks] = ks*1024 + kq*256 + lr*16;
    int woff[4];
#pragma unroll
    for (int nt = 0; nt < 4; ++nt){
        int c = c0 + nt*16 + kq*4;
        woff[nt] = (c >> 3)*256 + lr*16 + (c & 7)*2;
    }
    __hip_bfloat16* hob = hout + ((size_t)(b0+lr)*NS)*NH + c0;

    __syncthreads();   // bsh + h0 visible (once)

    // depth-2 prefetch: slots A (even steps) and B (odd steps)
    float4 xqA[4], xqB[4]; ushort4 bqA[4], bqB[4];
    if (LAYER == 0){
        int i0 = bsh[lr*NS + 0], i1 = bsh[lr*NS + 1];
#pragma unroll
        for (int nt = 0; nt < 4; ++nt){
            xqA[nt] = *reinterpret_cast<const float4*>(xf + (size_t)i0*NH + c0 + nt*16 + kq*4);
            xqB[nt] = *reinterpret_cast<const float4*>(xf + (size_t)i1*NH + c0 + nt*16 + kq*4);
        }
    } else {
        const unsigned short* s0 = xb + ((size_t)(b0+lr)*NS + 0)*NH;
        const unsigned short* s1 = xb + ((size_t)(b0+lr)*NS + 1)*NH;
#pragma unroll
        for (int nt = 0; nt < 4; ++nt){
            bqA[nt] = *reinterpret_cast<const ushort4*>(s0 + c0 + nt*16 + kq*4);
            bqB[nt] = *reinterpret_cast<const ushort4*>(s1 + c0 + nt*16 + kq*4);
        }
    }

    for (int s = 0; s < NS; s += 2){
        RNN_STEP(h0, h1, xqA, bqA, s);      // read h0, write h1
        BAR();
        RNN_STEP(h1, h0, xqB, bqB, s + 1);  // read h1, write h0
        BAR();
    }
}

// ---------------------------------------------------------------------------
// K3/K5: C[M,N] = A[M,256] @ W[N,256]^T (+bias1+bias2), MFMA 16x16x32 bf16.
// ---------------------------------------------------------------------------
template<int N>
__global__ void k_gemm(const __hip_bfloat16* __restrict__ A,
                       const __hip_bfloat16* __restrict__ W,
                       const __hip_bfloat16* __restrict__ bias1,
                       const __hip_bfloat16* __restrict__ bias2,
                       void* __restrict__ Cout, int ldc,
                       const void* __restrict__ probe){
    const bool f32out = probe ? detect_f32(probe) : false;
    const int m0 = blockIdx.x * 64;
    const int n0 = blockIdx.y * 64;
    const int wv = threadIdx.x >> 6;
    const int l  = threadIdx.x & 63;
    const int mrow  = m0 + wv*16 + (l & 15);
    const int kbase = (l >> 4) * 8;

    f32x4 acc[4] = {};
#pragma unroll
    for (int ks = 0; ks < 8; ++ks){
        bf16x8 af = *reinterpret_cast<const bf16x8*>(A + (size_t)mrow*NH + ks*32 + kbase);
#pragma unroll
        for (int nt = 0; nt < 4; ++nt){
            int ncol = n0 + nt*16 + (l & 15);
            int nc = (ncol < N) ? ncol : (N-1);
            bf16x8 bfr = *reinterpret_cast<const bf16x8*>(W + (size_t)nc*NH + ks*32 + kbase);
            acc[nt] = __builtin_amdgcn_mfma_f32_16x16x32_bf16(af, bfr, acc[nt], 0, 0, 0);
        }
    }
#pragma unroll
    for (int nt = 0; nt < 4; ++nt){
        int ncol = n0 + nt*16 + (l & 15);
        if (ncol >= N) continue;
        float bsum = __bfloat162float(bias1[ncol]) + (bias2 ? __bfloat162float(bias2[ncol]) : 0.f);
#pragma unroll
        for (int r = 0; r < 4; ++r){
            int row = m0 + wv*16 + (l>>4)*4 + r;
            float val = acc[nt][r] + bsum;
            if (f32out) ((float*)Cout)[(size_t)row*ldc + ncol] = val;
            else        ((__hip_bfloat16*)Cout)[(size_t)row*ldc + ncol] = __float2bfloat16(val);
        }
    }
}

// ---------------------------------------------------------------------------
extern "C" void kernel_launch(void* const* d_in, const int* in_sizes, int n_in,
                              void* d_out, int out_size, void* d_ws, size_t ws_size,
                              hipStream_t stream){
    const int* batch = (const int*)d_in[0];
    const void* probe = d_in[3];  // raw W_hh0 for dtype detection

    char* ws = (char*)d_ws;
    size_t off = 0;
    auto give = [&](size_t bytes)->char*{
        char* p = ws + off; off = (off + bytes + 511) & ~(size_t)511; return p;
    };
    __hip_bfloat16* cFeats = (__hip_bfloat16*)give(2*NV*NF);
    __hip_bfloat16* cWih0  = (__hip_bfloat16*)give(2*NH*NF);
    __hip_bfloat16* cWhh0  = (__hip_bfloat16*)give(2*NH*NH);
    __hip_bfloat16* cBih0  = (__hip_bfloat16*)give(2*NH);
    __hip_bfloat16* cBhh0  = (__hip_bfloat16*)give(2*NH);
    __hip_bfloat16* cWih1  = (__hip_bfloat16*)give(2*NH*NH);
    __hip_bfloat16* cWhh1  = (__hip_bfloat16*)give(2*NH*NH);
    __hip_bfloat16* cBih1  = (__hip_bfloat16*)give(2*NH);
    __hip_bfloat16* cBhh1  = (__hip_bfloat16*)give(2*NH);
    __hip_bfloat16* cWout  = (__hip_bfloat16*)give(2*NV*NH);
    __hip_bfloat16* cBout  = (__hip_bfloat16*)give(2*NV);
    float*          pre0   = (float*)give(4*NV*NH);
    __hip_bfloat16* hbuf   = (__hip_bfloat16*)give(2*(size_t)NB*NS*NH);
    __hip_bfloat16* xp1    = (__hip_bfloat16*)give(2*(size_t)NB*NS*NH);

    ConvArgs ca;
    const void* srcs[11] = { d_in[1], d_in[2], d_in[3], d_in[4], d_in[5], d_in[6],
                             d_in[7], d_in[8], d_in[9], d_in[10], d_in[11] };
    __hip_bfloat16* dsts[11] = { cFeats, cWih0, cWhh0, cBih0, cBhh0, cWih1,
                                 cWhh1, cBih1, cBhh1, cWout, cBout };
    int ns[11] = { NV*NF, NH*NF, NH*NH, NH, NH, NH*NH, NH*NH, NH, NH, NV*NH, NV };
    for (int i = 0; i < 11; ++i){ ca.src[i] = srcs[i]; ca.dst[i] = dsts[i]; ca.n[i] = ns[i]; }
    k_conv_all<<<dim3(500, 11), dim3(256), 0, stream>>>(ca, probe);

    k_pre0<<<dim3(NV), dim3(256), 0, stream>>>(cFeats, cWih0, cBih0, cBhh0, pre0);
    k_rnn<0><<<dim3(NB/16), dim3(256), 0, stream>>>(batch, pre0, cWhh0, hbuf);
    k_gemm<NH><<<dim3((NB*NS)/64, NH/64), dim3(256), 0, stream>>>(
        hbuf, cWih1, cBih1, cBhh1, xp1, NH, nullptr);
    k_rnn<1><<<dim3(NB/16), dim3(256), 0, stream>>>(batch, xp1, cWhh1, hbuf);
    k_gemm<NV><<<dim3((NB*NS)/64, 16), dim3(256), 0, stream>>>(
        hbuf, cWout, cBout, nullptr, d_out, NV, probe);
}

// Round 8
// 1089.344 us; speedup vs baseline: 1.0422x; 1.0354x over previous
//
#include <hip/hip_runtime.h>
#include <hip/hip_bf16.h>

#define NB 64
#define NS 512
#define NV 1000
#define NF 64
#define NH 256

typedef short bf16x8 __attribute__((ext_vector_type(8)));
typedef float f32x4 __attribute__((ext_vector_type(4)));

__device__ __forceinline__ float bf2f(unsigned int u16bits){
    union { unsigned int i; float f; } v;
    v.i = (u16bits & 0xffffu) << 16;
    return v.f;
}

__device__ __forceinline__ float tanh_fast(float x){
    float e = __builtin_amdgcn_exp2f(x * 2.8853900817779268f);
    return 1.f - 2.f * __builtin_amdgcn_rcpf(e + 1.f);
}

__device__ __forceinline__ bool detect_f32(const void* probe){
    const unsigned short* p = (const unsigned short*)probe;
    bool bad = false; float mx = 0.f;
#pragma unroll
    for (int j = 0; j < 64; ++j){
        float v = fabsf(bf2f(p[j]));
        bad = bad || !(v == v);
        mx = fmaxf(mx, v);
    }
    return bad || (mx > 100.f);
}

// ---------------------------------------------------------------------------
// K0: canonicalize all 11 float inputs into bf16 — ONE launch.
// ---------------------------------------------------------------------------
struct ConvArgs { const void* src[11]; __hip_bfloat16* dst[11]; int n[11]; };

__global__ void k_conv_all(ConvArgs a, const void* __restrict__ probe){
    const int seg = blockIdx.y;
    const int n = a.n[seg];
    int i = blockIdx.x * 256 + threadIdx.x;
    if (i >= n) return;
    const bool f32in = detect_f32(probe);
    const int stride = gridDim.x * 256;
    __hip_bfloat16* dst = a.dst[seg];
    if (f32in){
        const float* s = (const float*)a.src[seg];
        for (; i < n; i += stride) dst[i] = __float2bfloat16(s[i]);
    } else {
        const unsigned short* s = (const unsigned short*)a.src[seg];
        for (; i < n; i += stride) dst[i] = __float2bfloat16(bf2f(s[i]));
    }
}

// ---------------------------------------------------------------------------
// K1: pre0[v][h] = dot(features[v,:], W_ih0[h,:]) + b_ih0[h] + b_hh0[h]  (f32)
// ---------------------------------------------------------------------------
__global__ void k_pre0(const __hip_bfloat16* __restrict__ feats,
                       const __hip_bfloat16* __restrict__ Wih,
                       const __hip_bfloat16* __restrict__ bih,
                       const __hip_bfloat16* __restrict__ bhh,
                       float* __restrict__ pre0){
    const int v = blockIdx.x, h = threadIdx.x;
    __shared__ __align__(16) float fsh[NF];
    if (h < NF) fsh[h] = __bfloat162float(feats[v*NF + h]);
    __syncthreads();
    const uint4* wr = reinterpret_cast<const uint4*>(Wih + h*NF);
    float acc = __bfloat162float(bih[h]) + __bfloat162float(bhh[h]);
#pragma unroll
    for (int j = 0; j < 8; ++j){
        uint4 q = wr[j];
        const float* hf = &fsh[j*8];
        acc += hf[0]*bf2f(q.x) + hf[1]*bf2f(q.x>>16)
             + hf[2]*bf2f(q.y) + hf[3]*bf2f(q.y>>16)
             + hf[4]*bf2f(q.z) + hf[5]*bf2f(q.z>>16)
             + hf[6]*bf2f(q.w) + hf[7]*bf2f(q.w>>16);
    }
    pre0[v*NH + h] = acc;
}

// ---------------------------------------------------------------------------
// K2/K4: MFMA RNN recurrence. Grid = 4 WGs x 256 threads (4 waves), 16 batch
// rows per WG, 64 output cols per wave. Step = D = Whh @ H^T (+xp via C-op).
// Round-7 diagnosis: step is VALU-ISSUE-BOUND (~980cyc VALU of 2235). This
// version cuts VALU: acc-init=xp (C operand), v_cvt_pk_bf16_f32 packing,
// depth-4 static prefetch slots (no copies, no same-step vmcnt waits),
// strength-reduced addressing (imm offsets, one ptr bump per 4 steps).
// LDS H layout [k8][row]*16B: conflict-free reads+writes (round-6 verified).
// BAR = lgkmcnt-only barrier: global loads/stores pipeline across steps.
// ---------------------------------------------------------------------------
#define BAR() do { asm volatile("s_waitcnt lgkmcnt(0)" ::: "memory");  \
                   __builtin_amdgcn_s_barrier();                        \
                   asm volatile("" ::: "memory"); } while (0)

#define RNN_STEP4(RIMM, WIMM, XS, BS, IREG, SOFF)                                 \
  do {                                                                            \
    f32x4 acc[4];                                                                 \
    if (LAYER == 0){                                                              \
        _Pragma("unroll") for (int nt = 0; nt < 4; ++nt)                          \
            acc[nt] = *reinterpret_cast<const f32x4*>(&XS[nt]);                   \
    } else {                                                                      \
        _Pragma("unroll") for (int nt = 0; nt < 4; ++nt)                          \
            _Pragma("unroll") for (int r = 0; r < 4; ++r)                         \
                acc[nt][r] = bf2f(((const unsigned short*)&BS[nt])[r]);           \
    }                                                                             \
    /* issue prefetch for step S+4 into the same static slot */                   \
    if (LAYER == 0){                                                              \
        const float* gb = xf + (size_t)IREG*NH + cq;                              \
        _Pragma("unroll") for (int nt = 0; nt < 4; ++nt)                          \
            XS[nt] = *reinterpret_cast<const float4*>(gb + nt*16);                \
        int sn = s + (SOFF) + 8; sn = (sn < NS) ? sn : NS-1;                      \
        IREG = bsh[lr*NS + sn];      /* idx for step S+8, used next iter */       \
    } else {                                                                      \
        _Pragma("unroll") for (int nt = 0; nt < 4; ++nt)                          \
            BS[nt] = *reinterpret_cast<const ushort4*>(                           \
                xrow + ((SOFF)+4)*NH + nt*16);                                    \
    }                                                                             \
    bf16x8 hf[8];                                                                 \
    _Pragma("unroll") for (int ks = 0; ks < 8; ++ks)                              \
        hf[ks] = *reinterpret_cast<const bf16x8*>(hb + roff[ks] + (RIMM));        \
    _Pragma("unroll") for (int ks = 0; ks < 8; ++ks){                             \
        _Pragma("unroll") for (int nt = 0; nt < 4; ++nt)                          \
            acc[nt] = __builtin_amdgcn_mfma_f32_16x16x32_bf16(                    \
                wf[nt][ks], hf[ks], acc[nt], 0, 0, 0);                            \
    }                                                                             \
    _Pragma("unroll") for (int nt = 0; nt < 4; ++nt){                             \
        float t0 = tanh_fast(acc[nt][0]), t1 = tanh_fast(acc[nt][1]);             \
        float t2 = tanh_fast(acc[nt][2]), t3 = tanh_fast(acc[nt][3]);             \
        unsigned plo, phi;                                                        \
        asm("v_cvt_pk_bf16_f32 %0, %1, %2" : "=v"(plo) : "v"(t0), "v"(t1));       \
        asm("v_cvt_pk_bf16_f32 %0, %1, %2" : "=v"(phi) : "v"(t2), "v"(t3));       \
        uint2 p; p.x = plo; p.y = phi;                                            \
        *reinterpret_cast<uint2*>(wb + woff[nt] + (WIMM)) = p;                    \
        *reinterpret_cast<uint2*>(hop + (SOFF)*NH + nt*16) = p;                   \
    }                                                                             \
  } while (0)

template<int LAYER>
__global__ __launch_bounds__(256, 1) void k_rnn(const int* __restrict__ batch,
                                                const void* __restrict__ xpv,
                                                const __hip_bfloat16* __restrict__ Whh,
                                                __hip_bfloat16* __restrict__ hout){
    const int l  = threadIdx.x & 63;
    const int w  = threadIdx.x >> 6;   // 0..3
    const int b0 = blockIdx.x * 16;
    const int lr = l & 15;             // batch row (B/D) and Whh out-col (A)
    const int kq = l >> 4;             // 0..3 k-quarter
    const int c0 = w * 64;             // wave's output-col base
    const int cq = c0 + kq*4;          // per-thread column base

    // A-frags: Whh[c0+nt*16+lr][ks*32+kq*8 .. +8] — loaded once, pinned.
    bf16x8 wf[4][8];
#pragma unroll
    for (int nt = 0; nt < 4; ++nt)
#pragma unroll
        for (int ks = 0; ks < 8; ++ks){
            wf[nt][ks] = *reinterpret_cast<const bf16x8*>(
                Whh + (size_t)(c0 + nt*16 + lr)*NH + ks*32 + kq*8);
            asm volatile("" : "+v"(wf[nt][ks]));
        }

    __shared__ __align__(16) unsigned short hsh[8192];  // 2 x 8KB [k8][row]*16B
    __shared__ int bsh[16*NS];

    {
        uint4* z = reinterpret_cast<uint4*>(hsh);
        z[threadIdx.x] = uint4{0,0,0,0};
        z[threadIdx.x + 256] = uint4{0,0,0,0};
    }
    if (LAYER == 0){
        const int4* bsrc = reinterpret_cast<const int4*>(batch + (size_t)b0*NS);
        int4* bdst = reinterpret_cast<int4*>(bsh);
#pragma unroll
        for (int i = 0; i < 8; ++i)
            bdst[threadIdx.x + i*256] = bsrc[threadIdx.x + i*256];
    }

    const float* xf = (const float*)xpv;
    const unsigned short* xrow =
        (const unsigned short*)xpv + ((size_t)(b0+lr)*NS)*NH + cq;  // layer-1 base

    int roff[8];
#pragma unroll
    for (int ks = 0; ks < 8; ++ks)
        roff[ks] = ks*1024 + kq*256 + lr*16;
    int woff[4];
#pragma unroll
    for (int nt = 0; nt < 4; ++nt){
        int c = cq + nt*16;
        woff[nt] = (c >> 3)*256 + lr*16 + (c & 7)*2;
    }
    const char* hb = (const char*)hsh;
    char*       wb = (char*)hsh;
    __hip_bfloat16* hob = hout + ((size_t)(b0+lr)*NS)*NH + cq;

    __syncthreads();   // bsh + zeroed h0 visible

    // depth-4 prefetch: 4 static slots; idx regs at depth 8 (layer 0)
    float4  xq0[4], xq1[4], xq2[4], xq3[4];
    ushort4 bq0[4], bq1[4], bq2[4], bq3[4];
    int i0 = 0, i1 = 0, i2 = 0, i3 = 0;
    if (LAYER == 0){
#pragma unroll
        for (int j = 0; j < 4; ++j){
            int idx = bsh[lr*NS + j];
            const float* gb = xf + (size_t)idx*NH + cq;
            float4* slot = (j==0) ? xq0 : (j==1) ? xq1 : (j==2) ? xq2 : xq3;
#pragma unroll
            for (int nt = 0; nt < 4; ++nt)
                slot[nt] = *reinterpret_cast<const float4*>(gb + nt*16);
        }
        i0 = bsh[lr*NS + 4]; i1 = bsh[lr*NS + 5];
        i2 = bsh[lr*NS + 6]; i3 = bsh[lr*NS + 7];
    } else {
#pragma unroll
        for (int nt = 0; nt < 4; ++nt){
            bq0[nt] = *reinterpret_cast<const ushort4*>(xrow + 0*NH + nt*16);
            bq1[nt] = *reinterpret_cast<const ushort4*>(xrow + 1*NH + nt*16);
            bq2[nt] = *reinterpret_cast<const ushort4*>(xrow + 2*NH + nt*16);
            bq3[nt] = *reinterpret_cast<const ushort4*>(xrow + 3*NH + nt*16);
        }
    }

    for (int s = 0; s < NS; s += 4){
        __hip_bfloat16* hop = hob + (size_t)s*NH;
        RNN_STEP4(0,    8192, xq0, bq0, i0, 0); BAR();
        RNN_STEP4(8192, 0,    xq1, bq1, i1, 1); BAR();
        RNN_STEP4(0,    8192, xq2, bq2, i2, 2); BAR();
        RNN_STEP4(8192, 0,    xq3, bq3, i3, 3); BAR();
        if (LAYER == 1) xrow += 4*NH;
    }
}

// ---------------------------------------------------------------------------
// K3/K5: C[M,N] = A[M,256] @ W[N,256]^T (+bias1+bias2), MFMA 16x16x32 bf16.
// ---------------------------------------------------------------------------
template<int N>
__global__ void k_gemm(const __hip_bfloat16* __restrict__ A,
                       const __hip_bfloat16* __restrict__ W,
                       const __hip_bfloat16* __restrict__ bias1,
                       const __hip_bfloat16* __restrict__ bias2,
                       void* __restrict__ Cout, int ldc,
                       const void* __restrict__ probe){
    const bool f32out = probe ? detect_f32(probe) : false;
    const int m0 = blockIdx.x * 64;
    const int n0 = blockIdx.y * 64;
    const int wv = threadIdx.x >> 6;
    const int l  = threadIdx.x & 63;
    const int mrow  = m0 + wv*16 + (l & 15);
    const int kbase = (l >> 4) * 8;

    f32x4 acc[4] = {};
#pragma unroll
    for (int ks = 0; ks < 8; ++ks){
        bf16x8 af = *reinterpret_cast<const bf16x8*>(A + (size_t)mrow*NH + ks*32 + kbase);
#pragma unroll
        for (int nt = 0; nt < 4; ++nt){
            int ncol = n0 + nt*16 + (l & 15);
            int nc = (ncol < N) ? ncol : (N-1);
            bf16x8 bfr = *reinterpret_cast<const bf16x8*>(W + (size_t)nc*NH + ks*32 + kbase);
            acc[nt] = __builtin_amdgcn_mfma_f32_16x16x32_bf16(af, bfr, acc[nt], 0, 0, 0);
        }
    }
#pragma unroll
    for (int nt = 0; nt < 4; ++nt){
        int ncol = n0 + nt*16 + (l & 15);
        if (ncol >= N) continue;
        float bsum = __bfloat162float(bias1[ncol]) + (bias2 ? __bfloat162float(bias2[ncol]) : 0.f);
#pragma unroll
        for (int r = 0; r < 4; ++r){
            int row = m0 + wv*16 + (l>>4)*4 + r;
            float val = acc[nt][r] + bsum;
            if (f32out) ((float*)Cout)[(size_t)row*ldc + ncol] = val;
            else        ((__hip_bfloat16*)Cout)[(size_t)row*ldc + ncol] = __float2bfloat16(val);
        }
    }
}

// ---------------------------------------------------------------------------
extern "C" void kernel_launch(void* const* d_in, const int* in_sizes, int n_in,
                              void* d_out, int out_size, void* d_ws, size_t ws_size,
                              hipStream_t stream){
    const int* batch = (const int*)d_in[0];
    const void* probe = d_in[3];  // raw W_hh0 for dtype detection

    char* ws = (char*)d_ws;
    size_t off = 0;
    auto give = [&](size_t bytes)->char*{
        char* p = ws + off; off = (off + bytes + 511) & ~(size_t)511; return p;
    };
    __hip_bfloat16* cFeats = (__hip_bfloat16*)give(2*NV*NF);
    __hip_bfloat16* cWih0  = (__hip_bfloat16*)give(2*NH*NF);
    __hip_bfloat16* cWhh0  = (__hip_bfloat16*)give(2*NH*NH);
    __hip_bfloat16* cBih0  = (__hip_bfloat16*)give(2*NH);
    __hip_bfloat16* cBhh0  = (__hip_bfloat16*)give(2*NH);
    __hip_bfloat16* cWih1  = (__hip_bfloat16*)give(2*NH*NH);
    __hip_bfloat16* cWhh1  = (__hip_bfloat16*)give(2*NH*NH);
    __hip_bfloat16* cBih1  = (__hip_bfloat16*)give(2*NH);
    __hip_bfloat16* cBhh1  = (__hip_bfloat16*)give(2*NH);
    __hip_bfloat16* cWout  = (__hip_bfloat16*)give(2*NV*NH);
    __hip_bfloat16* cBout  = (__hip_bfloat16*)give(2*NV);
    float*          pre0   = (float*)give(4*NV*NH);
    __hip_bfloat16* hbuf   = (__hip_bfloat16*)give(2*(size_t)NB*NS*NH);
    __hip_bfloat16* xp1    = (__hip_bfloat16*)give(2*(size_t)NB*NS*NH + 8192); // +pad: tail prefetch

    ConvArgs ca;
    const void* srcs[11] = { d_in[1], d_in[2], d_in[3], d_in[4], d_in[5], d_in[6],
                             d_in[7], d_in[8], d_in[9], d_in[10], d_in[11] };
    __hip_bfloat16* dsts[11] = { cFeats, cWih0, cWhh0, cBih0, cBhh0, cWih1,
                                 cWhh1, cBih1, cBhh1, cWout, cBout };
    int ns[11] = { NV*NF, NH*NF, NH*NH, NH, NH, NH*NH, NH*NH, NH, NH, NV*NH, NV };
    for (int i = 0; i < 11; ++i){ ca.src[i] = srcs[i]; ca.dst[i] = dsts[i]; ca.n[i] = ns[i]; }
    k_conv_all<<<dim3(500, 11), dim3(256), 0, stream>>>(ca, probe);

    k_pre0<<<dim3(NV), dim3(256), 0, stream>>>(cFeats, cWih0, cBih0, cBhh0, pre0);
    k_rnn<0><<<dim3(NB/16), dim3(256), 0, stream>>>(batch, pre0, cWhh0, hbuf);
    k_gemm<NH><<<dim3((NB*NS)/64, NH/64), dim3(256), 0, stream>>>(
        hbuf, cWih1, cBih1, cBhh1, xp1, NH, nullptr);
    k_rnn<1><<<dim3(NB/16), dim3(256), 0, stream>>>(batch, xp1, cWhh1, hbuf);
    k_gemm<NV><<<dim3((NB*NS)/64, 16), dim3(256), 0, stream>>>(
        hbuf, cWout, cBout, nullptr, d_out, NV, probe);
}

// Round 9
// 992.001 us; speedup vs baseline: 1.1444x; 1.0981x over previous
//
#include <hip/hip_runtime.h>
#include <hip/hip_bf16.h>

#define NB 64
#define NS 512
#define NV 1000
#define NF 64
#define NH 256

typedef short bf16x8 __attribute__((ext_vector_type(8)));
typedef float f32x4 __attribute__((ext_vector_type(4)));

__device__ __forceinline__ float bf2f(unsigned int u16bits){
    union { unsigned int i; float f; } v;
    v.i = (u16bits & 0xffffu) << 16;
    return v.f;
}

__device__ __forceinline__ float tanh_fast(float x){
    float e = __builtin_amdgcn_exp2f(x * 2.8853900817779268f);
    return 1.f - 2.f * __builtin_amdgcn_rcpf(e + 1.f);
}

__device__ __forceinline__ bool detect_f32(const void* probe){
    const unsigned short* p = (const unsigned short*)probe;
    bool bad = false; float mx = 0.f;
#pragma unroll
    for (int j = 0; j < 64; ++j){
        float v = fabsf(bf2f(p[j]));
        bad = bad || !(v == v);
        mx = fmaxf(mx, v);
    }
    return bad || (mx > 100.f);
}

// ---------------------------------------------------------------------------
// K0: canonicalize all 11 float inputs into bf16 — ONE launch.
// ---------------------------------------------------------------------------
struct ConvArgs { const void* src[11]; __hip_bfloat16* dst[11]; int n[11]; };

__global__ void k_conv_all(ConvArgs a, const void* __restrict__ probe){
    const int seg = blockIdx.y;
    const int n = a.n[seg];
    int i = blockIdx.x * 256 + threadIdx.x;
    if (i >= n) return;
    const bool f32in = detect_f32(probe);
    const int stride = gridDim.x * 256;
    __hip_bfloat16* dst = a.dst[seg];
    if (f32in){
        const float* s = (const float*)a.src[seg];
        for (; i < n; i += stride) dst[i] = __float2bfloat16(s[i]);
    } else {
        const unsigned short* s = (const unsigned short*)a.src[seg];
        for (; i < n; i += stride) dst[i] = __float2bfloat16(bf2f(s[i]));
    }
}

// ---------------------------------------------------------------------------
// K1: pre0[v][h] = dot(features[v,:], W_ih0[h,:]) + b_ih0[h] + b_hh0[h]  (f32)
// ---------------------------------------------------------------------------
__global__ void k_pre0(const __hip_bfloat16* __restrict__ feats,
                       const __hip_bfloat16* __restrict__ Wih,
                       const __hip_bfloat16* __restrict__ bih,
                       const __hip_bfloat16* __restrict__ bhh,
                       float* __restrict__ pre0){
    const int v = blockIdx.x, h = threadIdx.x;
    __shared__ __align__(16) float fsh[NF];
    if (h < NF) fsh[h] = __bfloat162float(feats[v*NF + h]);
    __syncthreads();
    const uint4* wr = reinterpret_cast<const uint4*>(Wih + h*NF);
    float acc = __bfloat162float(bih[h]) + __bfloat162float(bhh[h]);
#pragma unroll
    for (int j = 0; j < 8; ++j){
        uint4 q = wr[j];
        const float* hf = &fsh[j*8];
        acc += hf[0]*bf2f(q.x) + hf[1]*bf2f(q.x>>16)
             + hf[2]*bf2f(q.y) + hf[3]*bf2f(q.y>>16)
             + hf[4]*bf2f(q.z) + hf[5]*bf2f(q.z>>16)
             + hf[6]*bf2f(q.w) + hf[7]*bf2f(q.w>>16);
    }
    pre0[v*NH + h] = acc;
}

// ---------------------------------------------------------------------------
// K2/K4: MFMA RNN recurrence. Grid = 4 WGs x 512 threads (8 WAVES, 32 cols
// each), 16 batch rows per WG. Round-8 diagnosis: 1 wave/SIMD serializes
// VALU(~700cyc: 16 tanh) + MFMA(~500) + LDS in one instruction stream.
// This version: 2 waves/SIMD so pipes overlap across waves; per wave only
// 16 MFMA + 8 tanh. launch_bounds(512,2) caps VGPR at 256.
// LDS H layout [k8][row]*16B: conflict-free reads+writes (round-6 verified).
// bsh padded to stride 513 ints (round-8: stride-512 put all lr in 1 bank).
// BAR = lgkmcnt-only barrier: global loads/stores pipeline across steps.
// ---------------------------------------------------------------------------
#define BAR() do { asm volatile("s_waitcnt lgkmcnt(0)" ::: "memory");  \
                   __builtin_amdgcn_s_barrier();                        \
                   asm volatile("" ::: "memory"); } while (0)

#define RNN_STEP4(RIMM, WIMM, XS, BS, IREG, SOFF)                                 \
  do {                                                                            \
    f32x4 acc[2];                                                                 \
    if (LAYER == 0){                                                              \
        _Pragma("unroll") for (int nt = 0; nt < 2; ++nt)                          \
            acc[nt] = *reinterpret_cast<const f32x4*>(&XS[nt]);                   \
    } else {                                                                      \
        _Pragma("unroll") for (int nt = 0; nt < 2; ++nt)                          \
            _Pragma("unroll") for (int r = 0; r < 4; ++r)                         \
                acc[nt][r] = bf2f(((const unsigned short*)&BS[nt])[r]);           \
    }                                                                             \
    /* issue prefetch for step S+4 into the same static slot */                   \
    if (LAYER == 0){                                                              \
        const float* gb = xf + (size_t)IREG*NH + cq;                              \
        _Pragma("unroll") for (int nt = 0; nt < 2; ++nt)                          \
            XS[nt] = *reinterpret_cast<const float4*>(gb + nt*16);                \
        int sn = s + (SOFF) + 8; sn = (sn < NS) ? sn : NS-1;                      \
        IREG = bsh[lr*513 + sn];     /* idx for step S+8, used next iter */       \
    } else {                                                                      \
        _Pragma("unroll") for (int nt = 0; nt < 2; ++nt)                          \
            BS[nt] = *reinterpret_cast<const ushort4*>(                           \
                xrow + ((SOFF)+4)*NH + nt*16);                                    \
    }                                                                             \
    bf16x8 hf[8];                                                                 \
    _Pragma("unroll") for (int ks = 0; ks < 8; ++ks)                              \
        hf[ks] = *reinterpret_cast<const bf16x8*>(hb + roff[ks] + (RIMM));        \
    _Pragma("unroll") for (int ks = 0; ks < 8; ++ks){                             \
        _Pragma("unroll") for (int nt = 0; nt < 2; ++nt)                          \
            acc[nt] = __builtin_amdgcn_mfma_f32_16x16x32_bf16(                    \
                wf[nt][ks], hf[ks], acc[nt], 0, 0, 0);                            \
    }                                                                             \
    _Pragma("unroll") for (int nt = 0; nt < 2; ++nt){                             \
        float t0 = tanh_fast(acc[nt][0]), t1 = tanh_fast(acc[nt][1]);             \
        float t2 = tanh_fast(acc[nt][2]), t3 = tanh_fast(acc[nt][3]);             \
        unsigned plo, phi;                                                        \
        asm("v_cvt_pk_bf16_f32 %0, %1, %2" : "=v"(plo) : "v"(t0), "v"(t1));       \
        asm("v_cvt_pk_bf16_f32 %0, %1, %2" : "=v"(phi) : "v"(t2), "v"(t3));       \
        uint2 p; p.x = plo; p.y = phi;                                            \
        *reinterpret_cast<uint2*>(wb + woff[nt] + (WIMM)) = p;                    \
        *reinterpret_cast<uint2*>(hop + (SOFF)*NH + nt*16) = p;                   \
    }                                                                             \
  } while (0)

template<int LAYER>
__global__ __launch_bounds__(512, 2) void k_rnn(const int* __restrict__ batch,
                                                const void* __restrict__ xpv,
                                                const __hip_bfloat16* __restrict__ Whh,
                                                __hip_bfloat16* __restrict__ hout){
    const int l  = threadIdx.x & 63;
    const int w  = threadIdx.x >> 6;   // 0..7
    const int b0 = blockIdx.x * 16;
    const int lr = l & 15;             // batch row (B/D) and Whh out-col (A)
    const int kq = l >> 4;             // 0..3 k-quarter
    const int c0 = w * 32;             // wave's output-col base (32 cols/wave)
    const int cq = c0 + kq*4;          // per-thread column base

    // A-frags: Whh[c0+nt*16+lr][ks*32+kq*8 .. +8] — loaded once, pinned.
    bf16x8 wf[2][8];
#pragma unroll
    for (int nt = 0; nt < 2; ++nt)
#pragma unroll
        for (int ks = 0; ks < 8; ++ks){
            wf[nt][ks] = *reinterpret_cast<const bf16x8*>(
                Whh + (size_t)(c0 + nt*16 + lr)*NH + ks*32 + kq*8);
            asm volatile("" : "+v"(wf[nt][ks]));
        }

    __shared__ __align__(16) unsigned short hsh[8192];  // 2 x 8KB [k8][row]*16B
    __shared__ int bsh[16*513];                         // padded stride: bank-spread

    {
        uint4* z = reinterpret_cast<uint4*>(hsh);
        z[threadIdx.x] = uint4{0,0,0,0};
        if (threadIdx.x < 512) z[threadIdx.x + 512] = uint4{0,0,0,0};
    }
    if (LAYER == 0){
        // copy batch[16][NS] -> bsh[16][513] (row r offset by +r)
        const int* bsrc = batch + (size_t)b0*NS;
#pragma unroll
        for (int k = 0; k < 16; ++k){
            int i = threadIdx.x + k*512;
            bsh[i + (i >> 9)] = bsrc[i];
        }
    }

    const float* xf = (const float*)xpv;
    const unsigned short* xrow =
        (const unsigned short*)xpv + ((size_t)(b0+lr)*NS)*NH + cq;  // layer-1 base

    int roff[8];
#pragma unroll
    for (int ks = 0; ks < 8; ++ks)
        roff[ks] = ks*1024 + kq*256 + lr*16;
    int woff[2];
#pragma unroll
    for (int nt = 0; nt < 2; ++nt){
        int c = cq + nt*16;
        woff[nt] = (c >> 3)*256 + lr*16 + (c & 7)*2;
    }
    const char* hb = (const char*)hsh;
    char*       wb = (char*)hsh;
    __hip_bfloat16* hob = hout + ((size_t)(b0+lr)*NS)*NH + cq;

    __syncthreads();   // bsh + zeroed h0 visible

    // depth-4 prefetch: 4 static slots; idx regs at depth 8 (layer 0)
    float4  xq0[2], xq1[2], xq2[2], xq3[2];
    ushort4 bq0[2], bq1[2], bq2[2], bq3[2];
    int i0 = 0, i1 = 0, i2 = 0, i3 = 0;
    if (LAYER == 0){
#pragma unroll
        for (int j = 0; j < 4; ++j){
            int idx = bsh[lr*513 + j];
            const float* gb = xf + (size_t)idx*NH + cq;
            float4* slot = (j==0) ? xq0 : (j==1) ? xq1 : (j==2) ? xq2 : xq3;
#pragma unroll
            for (int nt = 0; nt < 2; ++nt)
                slot[nt] = *reinterpret_cast<const float4*>(gb + nt*16);
        }
        i0 = bsh[lr*513 + 4]; i1 = bsh[lr*513 + 5];
        i2 = bsh[lr*513 + 6]; i3 = bsh[lr*513 + 7];
    } else {
#pragma unroll
        for (int nt = 0; nt < 2; ++nt){
            bq0[nt] = *reinterpret_cast<const ushort4*>(xrow + 0*NH + nt*16);
            bq1[nt] = *reinterpret_cast<const ushort4*>(xrow + 1*NH + nt*16);
            bq2[nt] = *reinterpret_cast<const ushort4*>(xrow + 2*NH + nt*16);
            bq3[nt] = *reinterpret_cast<const ushort4*>(xrow + 3*NH + nt*16);
        }
    }

    __hip_bfloat16* hop = hob;
    for (int s = 0; s < NS; s += 4){
        RNN_STEP4(0,    8192, xq0, bq0, i0, 0); BAR();
        RNN_STEP4(8192, 0,    xq1, bq1, i1, 1); BAR();
        RNN_STEP4(0,    8192, xq2, bq2, i2, 2); BAR();
        RNN_STEP4(8192, 0,    xq3, bq3, i3, 3); BAR();
        hop += 4*NH;
        if (LAYER == 1) xrow += 4*NH;
    }
}

// ---------------------------------------------------------------------------
// K3/K5: C[M,N] = A[M,256] @ W[N,256]^T (+bias1+bias2), MFMA 16x16x32 bf16.
// ---------------------------------------------------------------------------
template<int N>
__global__ void k_gemm(const __hip_bfloat16* __restrict__ A,
                       const __hip_bfloat16* __restrict__ W,
                       const __hip_bfloat16* __restrict__ bias1,
                       const __hip_bfloat16* __restrict__ bias2,
                       void* __restrict__ Cout, int ldc,
                       const void* __restrict__ probe){
    const bool f32out = probe ? detect_f32(probe) : false;
    const int m0 = blockIdx.x * 64;
    const int n0 = blockIdx.y * 64;
    const int wv = threadIdx.x >> 6;
    const int l  = threadIdx.x & 63;
    const int mrow  = m0 + wv*16 + (l & 15);
    const int kbase = (l >> 4) * 8;

    f32x4 acc[4] = {};
#pragma unroll
    for (int ks = 0; ks < 8; ++ks){
        bf16x8 af = *reinterpret_cast<const bf16x8*>(A + (size_t)mrow*NH + ks*32 + kbase);
#pragma unroll
        for (int nt = 0; nt < 4; ++nt){
            int ncol = n0 + nt*16 + (l & 15);
            int nc = (ncol < N) ? ncol : (N-1);
            bf16x8 bfr = *reinterpret_cast<const bf16x8*>(W + (size_t)nc*NH + ks*32 + kbase);
            acc[nt] = __builtin_amdgcn_mfma_f32_16x16x32_bf16(af, bfr, acc[nt], 0, 0, 0);
        }
    }
#pragma unroll
    for (int nt = 0; nt < 4; ++nt){
        int ncol = n0 + nt*16 + (l & 15);
        if (ncol >= N) continue;
        float bsum = __bfloat162float(bias1[ncol]) + (bias2 ? __bfloat162float(bias2[ncol]) : 0.f);
#pragma unroll
        for (int r = 0; r < 4; ++r){
            int row = m0 + wv*16 + (l>>4)*4 + r;
            float val = acc[nt][r] + bsum;
            if (f32out) ((float*)Cout)[(size_t)row*ldc + ncol] = val;
            else        ((__hip_bfloat16*)Cout)[(size_t)row*ldc + ncol] = __float2bfloat16(val);
        }
    }
}

// ---------------------------------------------------------------------------
extern "C" void kernel_launch(void* const* d_in, const int* in_sizes, int n_in,
                              void* d_out, int out_size, void* d_ws, size_t ws_size,
                              hipStream_t stream){
    const int* batch = (const int*)d_in[0];
    const void* probe = d_in[3];  // raw W_hh0 for dtype detection

    char* ws = (char*)d_ws;
    size_t off = 0;
    auto give = [&](size_t bytes)->char*{
        char* p = ws + off; off = (off + bytes + 511) & ~(size_t)511; return p;
    };
    __hip_bfloat16* cFeats = (__hip_bfloat16*)give(2*NV*NF);
    __hip_bfloat16* cWih0  = (__hip_bfloat16*)give(2*NH*NF);
    __hip_bfloat16* cWhh0  = (__hip_bfloat16*)give(2*NH*NH);
    __hip_bfloat16* cBih0  = (__hip_bfloat16*)give(2*NH);
    __hip_bfloat16* cBhh0  = (__hip_bfloat16*)give(2*NH);
    __hip_bfloat16* cWih1  = (__hip_bfloat16*)give(2*NH*NH);
    __hip_bfloat16* cWhh1  = (__hip_bfloat16*)give(2*NH*NH);
    __hip_bfloat16* cBih1  = (__hip_bfloat16*)give(2*NH);
    __hip_bfloat16* cBhh1  = (__hip_bfloat16*)give(2*NH);
    __hip_bfloat16* cWout  = (__hip_bfloat16*)give(2*NV*NH);
    __hip_bfloat16* cBout  = (__hip_bfloat16*)give(2*NV);
    float*          pre0   = (float*)give(4*NV*NH);
    __hip_bfloat16* hbuf   = (__hip_bfloat16*)give(2*(size_t)NB*NS*NH);
    __hip_bfloat16* xp1    = (__hip_bfloat16*)give(2*(size_t)NB*NS*NH + 8192); // +pad: tail prefetch

    ConvArgs ca;
    const void* srcs[11] = { d_in[1], d_in[2], d_in[3], d_in[4], d_in[5], d_in[6],
                             d_in[7], d_in[8], d_in[9], d_in[10], d_in[11] };
    __hip_bfloat16* dsts[11] = { cFeats, cWih0, cWhh0, cBih0, cBhh0, cWih1,
                                 cWhh1, cBih1, cBhh1, cWout, cBout };
    int ns[11] = { NV*NF, NH*NF, NH*NH, NH, NH, NH*NH, NH*NH, NH, NH, NV*NH, NV };
    for (int i = 0; i < 11; ++i){ ca.src[i] = srcs[i]; ca.dst[i] = dsts[i]; ca.n[i] = ns[i]; }
    k_conv_all<<<dim3(500, 11), dim3(256), 0, stream>>>(ca, probe);

    k_pre0<<<dim3(NV), dim3(256), 0, stream>>>(cFeats, cWih0, cBih0, cBhh0, pre0);
    k_rnn<0><<<dim3(NB/16), dim3(512), 0, stream>>>(batch, pre0, cWhh0, hbuf);
    k_gemm<NH><<<dim3((NB*NS)/64, NH/64), dim3(256), 0, stream>>>(
        hbuf, cWih1, cBih1, cBhh1, xp1, NH, nullptr);
    k_rnn<1><<<dim3(NB/16), dim3(512), 0, stream>>>(batch, xp1, cWhh1, hbuf);
    k_gemm<NV><<<dim3((NB*NS)/64, 16), dim3(256), 0, stream>>>(
        hbuf, cWout, cBout, nullptr, d_out, NV, probe);
}

// Round 10
// 883.003 us; speedup vs baseline: 1.2857x; 1.1234x over previous
//
#include <hip/hip_runtime.h>
#include <hip/hip_bf16.h>

#define NB 64
#define NS 512
#define NV 1000
#define NF 64
#define NH 256

typedef short bf16x8 __attribute__((ext_vector_type(8)));
typedef float f32x4 __attribute__((ext_vector_type(4)));

__device__ __forceinline__ float bf2f(unsigned int u16bits){
    union { unsigned int i; float f; } v;
    v.i = (u16bits & 0xffffu) << 16;
    return v.f;
}

__device__ __forceinline__ float tanh_fast(float x){
    float e = __builtin_amdgcn_exp2f(x * 2.8853900817779268f);
    return 1.f - 2.f * __builtin_amdgcn_rcpf(e + 1.f);
}

__device__ __forceinline__ bool detect_f32(const void* probe){
    const unsigned short* p = (const unsigned short*)probe;
    bool bad = false; float mx = 0.f;
#pragma unroll
    for (int j = 0; j < 64; ++j){
        float v = fabsf(bf2f(p[j]));
        bad = bad || !(v == v);
        mx = fmaxf(mx, v);
    }
    return bad || (mx > 100.f);
}

// ---------------------------------------------------------------------------
// K0: canonicalize all 11 float inputs into bf16 — ONE launch.
// ---------------------------------------------------------------------------
struct ConvArgs { const void* src[11]; __hip_bfloat16* dst[11]; int n[11]; };

__global__ void k_conv_all(ConvArgs a, const void* __restrict__ probe){
    const int seg = blockIdx.y;
    const int n = a.n[seg];
    int i = blockIdx.x * 256 + threadIdx.x;
    if (i >= n) return;
    const bool f32in = detect_f32(probe);
    const int stride = gridDim.x * 256;
    __hip_bfloat16* dst = a.dst[seg];
    if (f32in){
        const float* s = (const float*)a.src[seg];
        for (; i < n; i += stride) dst[i] = __float2bfloat16(s[i]);
    } else {
        const unsigned short* s = (const unsigned short*)a.src[seg];
        for (; i < n; i += stride) dst[i] = __float2bfloat16(bf2f(s[i]));
    }
}

// ---------------------------------------------------------------------------
// K1: pre0[v][h] = dot(features[v,:], W_ih0[h,:]) + b_ih0[h] + b_hh0[h] (bf16)
// ---------------------------------------------------------------------------
__global__ void k_pre0(const __hip_bfloat16* __restrict__ feats,
                       const __hip_bfloat16* __restrict__ Wih,
                       const __hip_bfloat16* __restrict__ bih,
                       const __hip_bfloat16* __restrict__ bhh,
                       __hip_bfloat16* __restrict__ pre0){
    const int v = blockIdx.x, h = threadIdx.x;
    __shared__ __align__(16) float fsh[NF];
    if (h < NF) fsh[h] = __bfloat162float(feats[v*NF + h]);
    __syncthreads();
    const uint4* wr = reinterpret_cast<const uint4*>(Wih + h*NF);
    float acc = __bfloat162float(bih[h]) + __bfloat162float(bhh[h]);
#pragma unroll
    for (int j = 0; j < 8; ++j){
        uint4 q = wr[j];
        const float* hf = &fsh[j*8];
        acc += hf[0]*bf2f(q.x) + hf[1]*bf2f(q.x>>16)
             + hf[2]*bf2f(q.y) + hf[3]*bf2f(q.y>>16)
             + hf[4]*bf2f(q.z) + hf[5]*bf2f(q.z>>16)
             + hf[6]*bf2f(q.w) + hf[7]*bf2f(q.w>>16);
    }
    pre0[v*NH + h] = __float2bfloat16(acc);
}

// ---------------------------------------------------------------------------
// K2: FUSED 2-layer RNN. 4 WGs x 512 threads (8 waves, 2 waves/SIMD),
// 16 batch rows/WG, 32 output cols/wave. Per step s, 3 chained MFMA phases:
//   A: acc0 = xp0(gathered pre0) ; acc0 += Whh0 @ H0[s-1]  -> tanh -> h0[s]
//      (h0[s] -> LDS only; NEVER touches HBM)
//   B: acc1 = bias1 ; acc1 += Wih1 @ h0[s]       (inter-layer GEMM, row-local)
//   C: acc1 += Whh1 @ H1[s-1] -> tanh -> h1[s] -> LDS + HBM(hbuf)
// Phase-B output layout == phase-C C-operand layout: zero repack.
// 3 weight sets (192 VGPR) pinned; hf read in chunks of 4; imm-offset LDS.
// LDS [k8][row]*16B layout, conflict-free; 2 lgkm-barriers/step.
// Eliminates: second 512-step pass + k_gemm<NH> + 32MB HBM round-trips.
// ---------------------------------------------------------------------------
#define BAR() do { asm volatile("s_waitcnt lgkmcnt(0)" ::: "memory");  \
                   __builtin_amdgcn_s_barrier();                        \
                   asm volatile("" ::: "memory"); } while (0)

#define PHASE(WF, BOFF, ACC)                                                      \
  _Pragma("unroll") for (int kc = 0; kc < 2; ++kc){                               \
    bf16x8 hfa[4];                                                                \
    _Pragma("unroll") for (int j = 0; j < 4; ++j)                                 \
      hfa[j] = *reinterpret_cast<const bf16x8*>(                                  \
          ldsb + (BOFF) + roffb + (kc*4 + j)*1024);                               \
    _Pragma("unroll") for (int j = 0; j < 4; ++j){                                \
      ACC[0] = __builtin_amdgcn_mfma_f32_16x16x32_bf16(WF[0][kc*4+j], hfa[j], ACC[0],0,0,0); \
      ACC[1] = __builtin_amdgcn_mfma_f32_16x16x32_bf16(WF[1][kc*4+j], hfa[j], ACC[1],0,0,0); \
    }                                                                             \
  }

#define TANH_PACK_STORE(ACC, WOFF, GSTORE, SPAR)                                  \
  _Pragma("unroll") for (int nt = 0; nt < 2; ++nt){                               \
    float t0 = tanh_fast(ACC[nt][0]), t1 = tanh_fast(ACC[nt][1]);                 \
    float t2 = tanh_fast(ACC[nt][2]), t3 = tanh_fast(ACC[nt][3]);                 \
    unsigned plo, phi;                                                            \
    asm("v_cvt_pk_bf16_f32 %0, %1, %2" : "=v"(plo) : "v"(t0), "v"(t1));           \
    asm("v_cvt_pk_bf16_f32 %0, %1, %2" : "=v"(phi) : "v"(t2), "v"(t3));           \
    uint2 p; p.x = plo; p.y = phi;                                                \
    *reinterpret_cast<uint2*>(ldsb + (WOFF) + woffb + nt*512) = p;                \
    if (GSTORE) *reinterpret_cast<uint2*>(hop + (SPAR)*NH + nt*16) = p;           \
  }

#define STEP(R0, W0, R1, W1, XS, IREG, SPAR)                                      \
  do {                                                                            \
    f32x4 acc0[2];                                                                \
    _Pragma("unroll") for (int nt = 0; nt < 2; ++nt)                              \
      _Pragma("unroll") for (int r = 0; r < 4; ++r)                               \
        acc0[nt][r] = bf2f(((const unsigned short*)&XS[nt])[r]);                  \
    { const unsigned short* gb = pre0b + (size_t)IREG*NH + cq;                    \
      XS[0] = *reinterpret_cast<const ushort4*>(gb);                              \
      XS[1] = *reinterpret_cast<const ushort4*>(gb + 16);                         \
      int sn = s + (SPAR) + 4; sn = (sn < NS) ? sn : NS - 1;                      \
      IREG = batch_g[sn]; }                                                       \
    PHASE(wf0, R0, acc0);                                                         \
    TANH_PACK_STORE(acc0, W0, 0, SPAR);                                           \
    BAR();                                                                        \
    f32x4 acc1[2]; acc1[0] = biasv[0]; acc1[1] = biasv[1];                        \
    PHASE(wfG, W0, acc1);                                                         \
    PHASE(wf1, R1, acc1);                                                         \
    TANH_PACK_STORE(acc1, W1, 1, SPAR);                                           \
    BAR();                                                                        \
  } while (0)

__global__ __launch_bounds__(512, 2) void k_rnn_fused(
        const int* __restrict__ batch,
        const unsigned short* __restrict__ pre0b,
        const __hip_bfloat16* __restrict__ Whh0,
        const __hip_bfloat16* __restrict__ Wih1,
        const __hip_bfloat16* __restrict__ Whh1,
        const __hip_bfloat16* __restrict__ bih1,
        const __hip_bfloat16* __restrict__ bhh1,
        __hip_bfloat16* __restrict__ hout){
    const int l  = threadIdx.x & 63;
    const int w  = threadIdx.x >> 6;   // 0..7
    const int b0 = blockIdx.x * 16;
    const int lr = l & 15;             // batch row (B/D cols) and weight out-col (A)
    const int kq = l >> 4;             // 0..3
    const int c0 = w * 32;             // wave's output-col base
    const int cq = c0 + kq*4;          // per-thread column base

    // 3 weight A-frag sets: [c0+nt*16+lr][ks*32+kq*8 ..+8] — loaded once, pinned.
    bf16x8 wf0[2][8], wfG[2][8], wf1[2][8];
#pragma unroll
    for (int nt = 0; nt < 2; ++nt)
#pragma unroll
        for (int ks = 0; ks < 8; ++ks){
            const size_t o = (size_t)(c0 + nt*16 + lr)*NH + ks*32 + kq*8;
            wf0[nt][ks] = *reinterpret_cast<const bf16x8*>(Whh0 + o);
            wfG[nt][ks] = *reinterpret_cast<const bf16x8*>(Wih1 + o);
            wf1[nt][ks] = *reinterpret_cast<const bf16x8*>(Whh1 + o);
            asm volatile("" : "+v"(wf0[nt][ks]));
            asm volatile("" : "+v"(wfG[nt][ks]));
            asm volatile("" : "+v"(wf1[nt][ks]));
        }

    // bias C-init for the inter-layer GEMM: row(=out col) dependent only.
    f32x4 biasv[2];
#pragma unroll
    for (int nt = 0; nt < 2; ++nt)
#pragma unroll
        for (int r = 0; r < 4; ++r){
            int c = cq + nt*16 + r;
            biasv[nt][r] = __bfloat162float(bih1[c]) + __bfloat162float(bhh1[c]);
        }

    // LDS: h0 dbuf @0/8192, h1 dbuf @16384/24576 ([k8][row]*16B chunks)
    __shared__ __align__(16) char lds_all[32768];
    char* ldsb = lds_all;
    *reinterpret_cast<uint4*>(ldsb + threadIdx.x*16)         = uint4{0,0,0,0}; // h0a
    *reinterpret_cast<uint4*>(ldsb + 16384 + threadIdx.x*16) = uint4{0,0,0,0}; // h1a

    const int roffb = kq*256 + lr*16;                       // + ks*1024 imm
    const int woffb = (cq >> 3)*256 + lr*16 + (cq & 7)*2;   // + nt*512 imm

    const int* batch_g = batch + (size_t)(b0 + lr)*NS;
    __hip_bfloat16* hop = hout + ((size_t)(b0+lr)*NS)*NH + cq;

    // depth-2 gather prefetch (slots A=even steps, B=odd), idx regs 4 ahead
    ushort4 xA[2], xB[2]; int iA, iB;
    {
        int j0 = batch_g[0], j1 = batch_g[1];
        const unsigned short* g0 = pre0b + (size_t)j0*NH + cq;
        const unsigned short* g1 = pre0b + (size_t)j1*NH + cq;
        xA[0] = *reinterpret_cast<const ushort4*>(g0);
        xA[1] = *reinterpret_cast<const ushort4*>(g0 + 16);
        xB[0] = *reinterpret_cast<const ushort4*>(g1);
        xB[1] = *reinterpret_cast<const ushort4*>(g1 + 16);
        iA = batch_g[2]; iB = batch_g[3];
    }
    __syncthreads();   // zeroed h0a/h1a visible

    for (int s = 0; s < NS; s += 2){
        STEP(0,    8192, 16384, 24576, xA, iA, 0);   // even: h0a->h0b, h1a->h1b
        STEP(8192, 0,    24576, 16384, xB, iB, 1);   // odd : h0b->h0a, h1b->h1a
        hop += 2*NH;
    }
}

// ---------------------------------------------------------------------------
// K3: C[M,N] = A[M,256] @ W[N,256]^T (+bias), MFMA 16x16x32 bf16.
// ---------------------------------------------------------------------------
template<int N>
__global__ void k_gemm(const __hip_bfloat16* __restrict__ A,
                       const __hip_bfloat16* __restrict__ W,
                       const __hip_bfloat16* __restrict__ bias1,
                       const __hip_bfloat16* __restrict__ bias2,
                       void* __restrict__ Cout, int ldc,
                       const void* __restrict__ probe){
    const bool f32out = probe ? detect_f32(probe) : false;
    const int m0 = blockIdx.x * 64;
    const int n0 = blockIdx.y * 64;
    const int wv = threadIdx.x >> 6;
    const int l  = threadIdx.x & 63;
    const int mrow  = m0 + wv*16 + (l & 15);
    const int kbase = (l >> 4) * 8;

    f32x4 acc[4] = {};
#pragma unroll
    for (int ks = 0; ks < 8; ++ks){
        bf16x8 af = *reinterpret_cast<const bf16x8*>(A + (size_t)mrow*NH + ks*32 + kbase);
#pragma unroll
        for (int nt = 0; nt < 4; ++nt){
            int ncol = n0 + nt*16 + (l & 15);
            int nc = (ncol < N) ? ncol : (N-1);
            bf16x8 bfr = *reinterpret_cast<const bf16x8*>(W + (size_t)nc*NH + ks*32 + kbase);
            acc[nt] = __builtin_amdgcn_mfma_f32_16x16x32_bf16(af, bfr, acc[nt], 0, 0, 0);
        }
    }
#pragma unroll
    for (int nt = 0; nt < 4; ++nt){
        int ncol = n0 + nt*16 + (l & 15);
        if (ncol >= N) continue;
        float bsum = __bfloat162float(bias1[ncol]) + (bias2 ? __bfloat162float(bias2[ncol]) : 0.f);
#pragma unroll
        for (int r = 0; r < 4; ++r){
            int row = m0 + wv*16 + (l>>4)*4 + r;
            float val = acc[nt][r] + bsum;
            if (f32out) ((float*)Cout)[(size_t)row*ldc + ncol] = val;
            else        ((__hip_bfloat16*)Cout)[(size_t)row*ldc + ncol] = __float2bfloat16(val);
        }
    }
}

// ---------------------------------------------------------------------------
extern "C" void kernel_launch(void* const* d_in, const int* in_sizes, int n_in,
                              void* d_out, int out_size, void* d_ws, size_t ws_size,
                              hipStream_t stream){
    const int* batch = (const int*)d_in[0];
    const void* probe = d_in[3];  // raw W_hh0 for dtype detection

    char* ws = (char*)d_ws;
    size_t off = 0;
    auto give = [&](size_t bytes)->char*{
        char* p = ws + off; off = (off + bytes + 511) & ~(size_t)511; return p;
    };
    __hip_bfloat16* cFeats = (__hip_bfloat16*)give(2*NV*NF);
    __hip_bfloat16* cWih0  = (__hip_bfloat16*)give(2*NH*NF);
    __hip_bfloat16* cWhh0  = (__hip_bfloat16*)give(2*NH*NH);
    __hip_bfloat16* cBih0  = (__hip_bfloat16*)give(2*NH);
    __hip_bfloat16* cBhh0  = (__hip_bfloat16*)give(2*NH);
    __hip_bfloat16* cWih1  = (__hip_bfloat16*)give(2*NH*NH);
    __hip_bfloat16* cWhh1  = (__hip_bfloat16*)give(2*NH*NH);
    __hip_bfloat16* cBih1  = (__hip_bfloat16*)give(2*NH);
    __hip_bfloat16* cBhh1  = (__hip_bfloat16*)give(2*NH);
    __hip_bfloat16* cWout  = (__hip_bfloat16*)give(2*NV*NH);
    __hip_bfloat16* cBout  = (__hip_bfloat16*)give(2*NV);
    __hip_bfloat16* pre0b  = (__hip_bfloat16*)give(2*NV*NH + 64);
    __hip_bfloat16* hbuf   = (__hip_bfloat16*)give(2*(size_t)NB*NS*NH);

    ConvArgs ca;
    const void* srcs[11] = { d_in[1], d_in[2], d_in[3], d_in[4], d_in[5], d_in[6],
                             d_in[7], d_in[8], d_in[9], d_in[10], d_in[11] };
    __hip_bfloat16* dsts[11] = { cFeats, cWih0, cWhh0, cBih0, cBhh0, cWih1,
                                 cWhh1, cBih1, cBhh1, cWout, cBout };
    int ns[11] = { NV*NF, NH*NF, NH*NH, NH, NH, NH*NH, NH*NH, NH, NH, NV*NH, NV };
    for (int i = 0; i < 11; ++i){ ca.src[i] = srcs[i]; ca.dst[i] = dsts[i]; ca.n[i] = ns[i]; }
    k_conv_all<<<dim3(500, 11), dim3(256), 0, stream>>>(ca, probe);

    k_pre0<<<dim3(NV), dim3(256), 0, stream>>>(cFeats, cWih0, cBih0, cBhh0, pre0b);
    k_rnn_fused<<<dim3(NB/16), dim3(512), 0, stream>>>(
        batch, (const unsigned short*)pre0b, cWhh0, cWih1, cWhh1, cBih1, cBhh1, hbuf);
    k_gemm<NV><<<dim3((NB*NS)/64, 16), dim3(256), 0, stream>>>(
        hbuf, cWout, cBout, nullptr, d_out, NV, probe);
}

// Round 12
// 823.780 us; speedup vs baseline: 1.3782x; 1.0719x over previous
//
#include <hip/hip_runtime.h>
#include <hip/hip_bf16.h>

#define NB 64
#define NS 512
#define NV 1000
#define NF 64
#define NH 256

typedef short bf16x8 __attribute__((ext_vector_type(8)));
typedef float f32x4 __attribute__((ext_vector_type(4)));

__device__ __forceinline__ float bf2f(unsigned int u16bits){
    union { unsigned int i; float f; } v;
    v.i = (u16bits & 0xffffu) << 16;
    return v.f;
}

__device__ __forceinline__ float tanh_fast(float x){
    float e = __builtin_amdgcn_exp2f(x * 2.8853900817779268f);
    return 1.f - 2.f * __builtin_amdgcn_rcpf(e + 1.f);
}

__device__ __forceinline__ bool detect_f32(const void* probe){
    const unsigned short* p = (const unsigned short*)probe;
    bool bad = false; float mx = 0.f;
#pragma unroll
    for (int j = 0; j < 64; ++j){
        float v = fabsf(bf2f(p[j]));
        bad = bad || !(v == v);
        mx = fmaxf(mx, v);
    }
    return bad || (mx > 100.f);
}

// ---------------------------------------------------------------------------
// K0: canonicalize all 11 float inputs into bf16 — ONE launch.
// ---------------------------------------------------------------------------
struct ConvArgs { const void* src[11]; __hip_bfloat16* dst[11]; int n[11]; };

__global__ void k_conv_all(ConvArgs a, const void* __restrict__ probe){
    const int seg = blockIdx.y;
    const int n = a.n[seg];
    int i = blockIdx.x * 256 + threadIdx.x;
    if (i >= n) return;
    const bool f32in = detect_f32(probe);
    const int stride = gridDim.x * 256;
    __hip_bfloat16* dst = a.dst[seg];
    if (f32in){
        const float* s = (const float*)a.src[seg];
        for (; i < n; i += stride) dst[i] = __float2bfloat16(s[i]);
    } else {
        const unsigned short* s = (const unsigned short*)a.src[seg];
        for (; i < n; i += stride) dst[i] = __float2bfloat16(bf2f(s[i]));
    }
}

// ---------------------------------------------------------------------------
// K1: pre0[v][h] = dot(features[v,:], W_ih0[h,:]) + b_ih0[h] + b_hh0[h] (bf16)
// ---------------------------------------------------------------------------
__global__ void k_pre0(const __hip_bfloat16* __restrict__ feats,
                       const __hip_bfloat16* __restrict__ Wih,
                       const __hip_bfloat16* __restrict__ bih,
                       const __hip_bfloat16* __restrict__ bhh,
                       __hip_bfloat16* __restrict__ pre0){
    const int v = blockIdx.x, h = threadIdx.x;
    __shared__ __align__(16) float fsh[NF];
    if (h < NF) fsh[h] = __bfloat162float(feats[v*NF + h]);
    __syncthreads();
    const uint4* wr = reinterpret_cast<const uint4*>(Wih + h*NF);
    float acc = __bfloat162float(bih[h]) + __bfloat162float(bhh[h]);
#pragma unroll
    for (int j = 0; j < 8; ++j){
        uint4 q = wr[j];
        const float* hf = &fsh[j*8];
        acc += hf[0]*bf2f(q.x) + hf[1]*bf2f(q.x>>16)
             + hf[2]*bf2f(q.y) + hf[3]*bf2f(q.y>>16)
             + hf[4]*bf2f(q.z) + hf[5]*bf2f(q.z>>16)
             + hf[6]*bf2f(q.w) + hf[7]*bf2f(q.w>>16);
    }
    pre0[v*NH + h] = __float2bfloat16(acc);
}

// ---------------------------------------------------------------------------
// K2: FUSED 2-layer RNN (round-10 passing structure + early phase-C reads).
// 4 WGs x 512 threads (8 waves, 2/SIMD), 16 batch rows/WG, 32 cols/wave.
// Per step: [early: read h1[s-1] frags into regs] A: h0-matvec -> tanh ->
// h0 LDS; BAR; C: Whh1@h1[s-1] from PRELOADED regs (MFMAs issue instantly);
// B: Wih1@h0[s] (ds_reads fly under C's MFMAs); tanh -> h1 LDS+HBM; BAR.
// Early C-reads are legal: buffer R1 is stable since previous end barrier,
// and nothing writes it this step. All loads compiler-visible (rule #18 n/a).
// ---------------------------------------------------------------------------
#define BAR() do { asm volatile("s_waitcnt lgkmcnt(0)" ::: "memory");  \
                   __builtin_amdgcn_s_barrier();                        \
                   asm volatile("" ::: "memory"); } while (0)

#define PHASE(WF, BOFF, ACC)                                                      \
  _Pragma("unroll") for (int kc = 0; kc < 2; ++kc){                               \
    bf16x8 hfa[4];                                                                \
    _Pragma("unroll") for (int j = 0; j < 4; ++j)                                 \
      hfa[j] = *reinterpret_cast<const bf16x8*>(                                  \
          ldsb + (BOFF) + roffb + (kc*4 + j)*1024);                               \
    _Pragma("unroll") for (int j = 0; j < 4; ++j){                                \
      ACC[0] = __builtin_amdgcn_mfma_f32_16x16x32_bf16(WF[0][kc*4+j], hfa[j], ACC[0],0,0,0); \
      ACC[1] = __builtin_amdgcn_mfma_f32_16x16x32_bf16(WF[1][kc*4+j], hfa[j], ACC[1],0,0,0); \
    }                                                                             \
  }

#define PHASER(WF, HARR, ACC)                                                     \
  _Pragma("unroll") for (int ks = 0; ks < 8; ++ks){                               \
    ACC[0] = __builtin_amdgcn_mfma_f32_16x16x32_bf16(WF[0][ks], HARR[ks], ACC[0],0,0,0); \
    ACC[1] = __builtin_amdgcn_mfma_f32_16x16x32_bf16(WF[1][ks], HARR[ks], ACC[1],0,0,0); \
  }

#define TANH_PACK_STORE(ACC, WOFF, GSTORE, SPAR)                                  \
  _Pragma("unroll") for (int nt = 0; nt < 2; ++nt){                               \
    float t0 = tanh_fast(ACC[nt][0]), t1 = tanh_fast(ACC[nt][1]);                 \
    float t2 = tanh_fast(ACC[nt][2]), t3 = tanh_fast(ACC[nt][3]);                 \
    unsigned plo, phi;                                                            \
    asm("v_cvt_pk_bf16_f32 %0, %1, %2" : "=v"(plo) : "v"(t0), "v"(t1));           \
    asm("v_cvt_pk_bf16_f32 %0, %1, %2" : "=v"(phi) : "v"(t2), "v"(t3));           \
    uint2 p; p.x = plo; p.y = phi;                                                \
    *reinterpret_cast<uint2*>(ldsb + (WOFF) + woffb + nt*512) = p;                \
    if (GSTORE) *reinterpret_cast<uint2*>(hop + (SPAR)*NH + nt*16) = p;           \
  }

#define STEP(R0, W0, R1, W1, XS, IREG, SPAR)                                      \
  do {                                                                            \
    /* EARLY: h1[s-1] B-frags (buffer R1 stable since prev end barrier) */        \
    bf16x8 hC[8];                                                                 \
    _Pragma("unroll") for (int ks = 0; ks < 8; ++ks)                              \
      hC[ks] = *reinterpret_cast<const bf16x8*>(ldsb + (R1) + roffb + ks*1024);   \
    f32x4 acc0[2];                                                                \
    _Pragma("unroll") for (int nt = 0; nt < 2; ++nt)                              \
      _Pragma("unroll") for (int r = 0; r < 4; ++r)                               \
        acc0[nt][r] = bf2f(((const unsigned short*)&XS[nt])[r]);                  \
    { const unsigned short* gb = pre0b + (size_t)IREG*NH + cq;                    \
      XS[0] = *reinterpret_cast<const ushort4*>(gb);                              \
      XS[1] = *reinterpret_cast<const ushort4*>(gb + 16);                         \
      int sn = s + (SPAR) + 4; sn = (sn < NS) ? sn : NS - 1;                      \
      IREG = batch_g[sn]; }                                                       \
    PHASE(wf0, R0, acc0);                                                         \
    TANH_PACK_STORE(acc0, W0, 0, SPAR);                                           \
    BAR();                                                                        \
    f32x4 acc1[2]; acc1[0] = biasv[0]; acc1[1] = biasv[1];                        \
    PHASER(wf1, hC, acc1);      /* C first: operands already in regs */           \
    PHASE(wfG, W0, acc1);       /* B: ds_reads overlap C's MFMAs */               \
    TANH_PACK_STORE(acc1, W1, 1, SPAR);                                           \
    BAR();                                                                        \
  } while (0)

__global__ __launch_bounds__(512, 2) void k_rnn_fused(
        const int* __restrict__ batch,
        const unsigned short* __restrict__ pre0b,
        const __hip_bfloat16* __restrict__ Whh0,
        const __hip_bfloat16* __restrict__ Wih1,
        const __hip_bfloat16* __restrict__ Whh1,
        const __hip_bfloat16* __restrict__ bih1,
        const __hip_bfloat16* __restrict__ bhh1,
        __hip_bfloat16* __restrict__ hout){
    const int l  = threadIdx.x & 63;
    const int w  = threadIdx.x >> 6;   // 0..7
    const int b0 = blockIdx.x * 16;
    const int lr = l & 15;             // batch row (B/D cols) and weight out-col (A)
    const int kq = l >> 4;             // 0..3
    const int c0 = w * 32;             // wave's output-col base
    const int cq = c0 + kq*4;          // per-thread column base

    // 3 weight A-frag sets: [c0+nt*16+lr][ks*32+kq*8 ..+8] — loaded once, pinned.
    bf16x8 wf0[2][8], wfG[2][8], wf1[2][8];
#pragma unroll
    for (int nt = 0; nt < 2; ++nt)
#pragma unroll
        for (int ks = 0; ks < 8; ++ks){
            const size_t o = (size_t)(c0 + nt*16 + lr)*NH + ks*32 + kq*8;
            wf0[nt][ks] = *reinterpret_cast<const bf16x8*>(Whh0 + o);
            wfG[nt][ks] = *reinterpret_cast<const bf16x8*>(Wih1 + o);
            wf1[nt][ks] = *reinterpret_cast<const bf16x8*>(Whh1 + o);
            asm volatile("" : "+v"(wf0[nt][ks]));
            asm volatile("" : "+v"(wfG[nt][ks]));
            asm volatile("" : "+v"(wf1[nt][ks]));
        }

    // bias C-init for the inter-layer GEMM: row(=out col) dependent only.
    f32x4 biasv[2];
#pragma unroll
    for (int nt = 0; nt < 2; ++nt)
#pragma unroll
        for (int r = 0; r < 4; ++r){
            int c = cq + nt*16 + r;
            biasv[nt][r] = __bfloat162float(bih1[c]) + __bfloat162float(bhh1[c]);
        }

    // LDS: h0 dbuf @0/8192, h1 dbuf @16384/24576 ([k8][row]*16B chunks)
    __shared__ __align__(16) char lds_all[32768];
    char* ldsb = lds_all;
    *reinterpret_cast<uint4*>(ldsb + threadIdx.x*16)         = uint4{0,0,0,0}; // h0a
    *reinterpret_cast<uint4*>(ldsb + 16384 + threadIdx.x*16) = uint4{0,0,0,0}; // h1a

    const int roffb = kq*256 + lr*16;                       // + ks*1024 imm
    const int woffb = (cq >> 3)*256 + lr*16 + (cq & 7)*2;   // + nt*512 imm

    const int* batch_g = batch + (size_t)(b0 + lr)*NS;
    __hip_bfloat16* hop = hout + ((size_t)(b0+lr)*NS)*NH + cq;

    // depth-2 gather prefetch (slots A=even steps, B=odd), idx regs 4 ahead
    ushort4 xA[2], xB[2]; int iA, iB;
    {
        int j0 = batch_g[0], j1 = batch_g[1];
        const unsigned short* g0 = pre0b + (size_t)j0*NH + cq;
        const unsigned short* g1 = pre0b + (size_t)j1*NH + cq;
        xA[0] = *reinterpret_cast<const ushort4*>(g0);
        xA[1] = *reinterpret_cast<const ushort4*>(g0 + 16);
        xB[0] = *reinterpret_cast<const ushort4*>(g1);
        xB[1] = *reinterpret_cast<const ushort4*>(g1 + 16);
        iA = batch_g[2]; iB = batch_g[3];
    }
    __syncthreads();   // zeroed h0a/h1a visible

    for (int s = 0; s < NS; s += 2){
        STEP(0,    8192, 16384, 24576, xA, iA, 0);   // even: h0a->h0b, h1a->h1b
        STEP(8192, 0,    24576, 16384, xB, iB, 1);   // odd : h0b->h0a, h1b->h1a
        hop += 2*NH;
    }
}

// ---------------------------------------------------------------------------
// K3: C[M,N] = A[M,256] @ W[N,256]^T (+bias), MFMA 16x16x32 bf16.
// ---------------------------------------------------------------------------
template<int N>
__global__ void k_gemm(const __hip_bfloat16* __restrict__ A,
                       const __hip_bfloat16* __restrict__ W,
                       const __hip_bfloat16* __restrict__ bias1,
                       const __hip_bfloat16* __restrict__ bias2,
                       void* __restrict__ Cout, int ldc,
                       const void* __restrict__ probe){
    const bool f32out = probe ? detect_f32(probe) : false;
    const int m0 = blockIdx.x * 64;
    const int n0 = blockIdx.y * 64;
    const int wv = threadIdx.x >> 6;
    const int l  = threadIdx.x & 63;
    const int mrow  = m0 + wv*16 + (l & 15);
    const int kbase = (l >> 4) * 8;

    f32x4 acc[4] = {};
#pragma unroll
    for (int ks = 0; ks < 8; ++ks){
        bf16x8 af = *reinterpret_cast<const bf16x8*>(A + (size_t)mrow*NH + ks*32 + kbase);
#pragma unroll
        for (int nt = 0; nt < 4; ++nt){
            int ncol = n0 + nt*16 + (l & 15);
            int nc = (ncol < N) ? ncol : (N-1);
            bf16x8 bfr = *reinterpret_cast<const bf16x8*>(W + (size_t)nc*NH + ks*32 + kbase);
            acc[nt] = __builtin_amdgcn_mfma_f32_16x16x32_bf16(af, bfr, acc[nt], 0, 0, 0);
        }
    }
#pragma unroll
    for (int nt = 0; nt < 4; ++nt){
        int ncol = n0 + nt*16 + (l & 15);
        if (ncol >= N) continue;
        float bsum = __bfloat162float(bias1[ncol]) + (bias2 ? __bfloat162float(bias2[ncol]) : 0.f);
#pragma unroll
        for (int r = 0; r < 4; ++r){
            int row = m0 + wv*16 + (l>>4)*4 + r;
            float val = acc[nt][r] + bsum;
            if (f32out) ((float*)Cout)[(size_t)row*ldc + ncol] = val;
            else        ((__hip_bfloat16*)Cout)[(size_t)row*ldc + ncol] = __float2bfloat16(val);
        }
    }
}

// ---------------------------------------------------------------------------
extern "C" void kernel_launch(void* const* d_in, const int* in_sizes, int n_in,
                              void* d_out, int out_size, void* d_ws, size_t ws_size,
                              hipStream_t stream){
    const int* batch = (const int*)d_in[0];
    const void* probe = d_in[3];  // raw W_hh0 for dtype detection

    char* ws = (char*)d_ws;
    size_t off = 0;
    auto give = [&](size_t bytes)->char*{
        char* p = ws + off; off = (off + bytes + 511) & ~(size_t)511; return p;
    };
    __hip_bfloat16* cFeats = (__hip_bfloat16*)give(2*NV*NF);
    __hip_bfloat16* cWih0  = (__hip_bfloat16*)give(2*NH*NF);
    __hip_bfloat16* cWhh0  = (__hip_bfloat16*)give(2*NH*NH);
    __hip_bfloat16* cBih0  = (__hip_bfloat16*)give(2*NH);
    __hip_bfloat16* cBhh0  = (__hip_bfloat16*)give(2*NH);
    __hip_bfloat16* cWih1  = (__hip_bfloat16*)give(2*NH*NH);
    __hip_bfloat16* cWhh1  = (__hip_bfloat16*)give(2*NH*NH);
    __hip_bfloat16* cBih1  = (__hip_bfloat16*)give(2*NH);
    __hip_bfloat16* cBhh1  = (__hip_bfloat16*)give(2*NH);
    __hip_bfloat16* cWout  = (__hip_bfloat16*)give(2*NV*NH);
    __hip_bfloat16* cBout  = (__hip_bfloat16*)give(2*NV);
    __hip_bfloat16* pre0b  = (__hip_bfloat16*)give(2*NV*NH + 64);
    __hip_bfloat16* hbuf   = (__hip_bfloat16*)give(2*(size_t)NB*NS*NH);

    ConvArgs ca;
    const void* srcs[11] = { d_in[1], d_in[2], d_in[3], d_in[4], d_in[5], d_in[6],
                             d_in[7], d_in[8], d_in[9], d_in[10], d_in[11] };
    __hip_bfloat16* dsts[11] = { cFeats, cWih0, cWhh0, cBih0, cBhh0, cWih1,
                                 cWhh1, cBih1, cBhh1, cWout, cBout };
    int ns[11] = { NV*NF, NH*NF, NH*NH, NH, NH, NH*NH, NH*NH, NH, NH, NV*NH, NV };
    for (int i = 0; i < 11; ++i){ ca.src[i] = srcs[i]; ca.dst[i] = dsts[i]; ca.n[i] = ns[i]; }
    k_conv_all<<<dim3(500, 11), dim3(256), 0, stream>>>(ca, probe);

    k_pre0<<<dim3(NV), dim3(256), 0, stream>>>(cFeats, cWih0, cBih0, cBhh0, pre0b);
    k_rnn_fused<<<dim3(NB/16), dim3(512), 0, stream>>>(
        batch, (const unsigned short*)pre0b, cWhh0, cWih1, cWhh1, cBih1, cBhh1, hbuf);
    k_gemm<NV><<<dim3((NB*NS)/64, 16), dim3(256), 0, stream>>>(
        hbuf, cWout, cBout, nullptr, d_out, NV, probe);
}

// Round 13
// 747.358 us; speedup vs baseline: 1.5191x; 1.1023x over previous
//
#include <hip/hip_runtime.h>
#include <hip/hip_bf16.h>

#define NB 64
#define NS 512
#define NV 1000
#define NF 64
#define NH 256

typedef short bf16x8 __attribute__((ext_vector_type(8)));
typedef float f32x4 __attribute__((ext_vector_type(4)));

__device__ __forceinline__ float bf2f(unsigned int u16bits){
    union { unsigned int i; float f; } v;
    v.i = (u16bits & 0xffffu) << 16;
    return v.f;
}

__device__ __forceinline__ float tanh_fast(float x){
    float e = __builtin_amdgcn_exp2f(x * 2.8853900817779268f);
    return 1.f - 2.f * __builtin_amdgcn_rcpf(e + 1.f);
}

__device__ __forceinline__ bool detect_f32(const void* probe){
    const unsigned short* p = (const unsigned short*)probe;
    bool bad = false; float mx = 0.f;
#pragma unroll
    for (int j = 0; j < 64; ++j){
        float v = fabsf(bf2f(p[j]));
        bad = bad || !(v == v);
        mx = fmaxf(mx, v);
    }
    return bad || (mx > 100.f);
}

// ---------------------------------------------------------------------------
// K0: canonicalize all 11 float inputs into bf16 — ONE launch.
// ---------------------------------------------------------------------------
struct ConvArgs { const void* src[11]; __hip_bfloat16* dst[11]; int n[11]; };

__global__ void k_conv_all(ConvArgs a, const void* __restrict__ probe){
    const int seg = blockIdx.y;
    const int n = a.n[seg];
    int i = blockIdx.x * 256 + threadIdx.x;
    if (i >= n) return;
    const bool f32in = detect_f32(probe);
    const int stride = gridDim.x * 256;
    __hip_bfloat16* dst = a.dst[seg];
    if (f32in){
        const float* s = (const float*)a.src[seg];
        for (; i < n; i += stride) dst[i] = __float2bfloat16(s[i]);
    } else {
        const unsigned short* s = (const unsigned short*)a.src[seg];
        for (; i < n; i += stride) dst[i] = __float2bfloat16(bf2f(s[i]));
    }
}

// ---------------------------------------------------------------------------
// K1: pre0[v][h] = dot(features[v,:], W_ih0[h,:]) + b_ih0[h] + b_hh0[h] (bf16)
// ---------------------------------------------------------------------------
__global__ void k_pre0(const __hip_bfloat16* __restrict__ feats,
                       const __hip_bfloat16* __restrict__ Wih,
                       const __hip_bfloat16* __restrict__ bih,
                       const __hip_bfloat16* __restrict__ bhh,
                       __hip_bfloat16* __restrict__ pre0){
    const int v = blockIdx.x, h = threadIdx.x;
    __shared__ __align__(16) float fsh[NF];
    if (h < NF) fsh[h] = __bfloat162float(feats[v*NF + h]);
    __syncthreads();
    const uint4* wr = reinterpret_cast<const uint4*>(Wih + h*NF);
    float acc = __bfloat162float(bih[h]) + __bfloat162float(bhh[h]);
#pragma unroll
    for (int j = 0; j < 8; ++j){
        uint4 q = wr[j];
        const float* hf = &fsh[j*8];
        acc += hf[0]*bf2f(q.x) + hf[1]*bf2f(q.x>>16)
             + hf[2]*bf2f(q.y) + hf[3]*bf2f(q.y>>16)
             + hf[4]*bf2f(q.z) + hf[5]*bf2f(q.z>>16)
             + hf[6]*bf2f(q.w) + hf[7]*bf2f(q.w>>16);
    }
    pre0[v*NH + h] = __float2bfloat16(acc);
}

// ---------------------------------------------------------------------------
// K2: FUSED 2-layer RNN (round-12 passing structure, FROZEN).
// 4 WGs x 512 threads (8 waves, 2/SIMD), 16 batch rows/WG, 32 cols/wave.
// Per step: [early: read h1[s-1] frags into regs] A: h0-matvec -> tanh ->
// h0 LDS; BAR; C: Whh1@h1[s-1] from PRELOADED regs; B: Wih1@h0[s] (ds_reads
// fly under C's MFMAs); tanh -> h1 LDS+HBM; BAR.
// ---------------------------------------------------------------------------
#define BAR() do { asm volatile("s_waitcnt lgkmcnt(0)" ::: "memory");  \
                   __builtin_amdgcn_s_barrier();                        \
                   asm volatile("" ::: "memory"); } while (0)

#define PHASE(WF, BOFF, ACC)                                                      \
  _Pragma("unroll") for (int kc = 0; kc < 2; ++kc){                               \
    bf16x8 hfa[4];                                                                \
    _Pragma("unroll") for (int j = 0; j < 4; ++j)                                 \
      hfa[j] = *reinterpret_cast<const bf16x8*>(                                  \
          ldsb + (BOFF) + roffb + (kc*4 + j)*1024);                               \
    _Pragma("unroll") for (int j = 0; j < 4; ++j){                                \
      ACC[0] = __builtin_amdgcn_mfma_f32_16x16x32_bf16(WF[0][kc*4+j], hfa[j], ACC[0],0,0,0); \
      ACC[1] = __builtin_amdgcn_mfma_f32_16x16x32_bf16(WF[1][kc*4+j], hfa[j], ACC[1],0,0,0); \
    }                                                                             \
  }

#define PHASER(WF, HARR, ACC)                                                     \
  _Pragma("unroll") for (int ks = 0; ks < 8; ++ks){                               \
    ACC[0] = __builtin_amdgcn_mfma_f32_16x16x32_bf16(WF[0][ks], HARR[ks], ACC[0],0,0,0); \
    ACC[1] = __builtin_amdgcn_mfma_f32_16x16x32_bf16(WF[1][ks], HARR[ks], ACC[1],0,0,0); \
  }

#define TANH_PACK_STORE(ACC, WOFF, GSTORE, SPAR)                                  \
  _Pragma("unroll") for (int nt = 0; nt < 2; ++nt){                               \
    float t0 = tanh_fast(ACC[nt][0]), t1 = tanh_fast(ACC[nt][1]);                 \
    float t2 = tanh_fast(ACC[nt][2]), t3 = tanh_fast(ACC[nt][3]);                 \
    unsigned plo, phi;                                                            \
    asm("v_cvt_pk_bf16_f32 %0, %1, %2" : "=v"(plo) : "v"(t0), "v"(t1));           \
    asm("v_cvt_pk_bf16_f32 %0, %1, %2" : "=v"(phi) : "v"(t2), "v"(t3));           \
    uint2 p; p.x = plo; p.y = phi;                                                \
    *reinterpret_cast<uint2*>(ldsb + (WOFF) + woffb + nt*512) = p;                \
    if (GSTORE) *reinterpret_cast<uint2*>(hop + (SPAR)*NH + nt*16) = p;           \
  }

#define STEP(R0, W0, R1, W1, XS, IREG, SPAR)                                      \
  do {                                                                            \
    bf16x8 hC[8];                                                                 \
    _Pragma("unroll") for (int ks = 0; ks < 8; ++ks)                              \
      hC[ks] = *reinterpret_cast<const bf16x8*>(ldsb + (R1) + roffb + ks*1024);   \
    f32x4 acc0[2];                                                                \
    _Pragma("unroll") for (int nt = 0; nt < 2; ++nt)                              \
      _Pragma("unroll") for (int r = 0; r < 4; ++r)                               \
        acc0[nt][r] = bf2f(((const unsigned short*)&XS[nt])[r]);                  \
    { const unsigned short* gb = pre0b + (size_t)IREG*NH + cq;                    \
      XS[0] = *reinterpret_cast<const ushort4*>(gb);                              \
      XS[1] = *reinterpret_cast<const ushort4*>(gb + 16);                         \
      int sn = s + (SPAR) + 4; sn = (sn < NS) ? sn : NS - 1;                      \
      IREG = batch_g[sn]; }                                                       \
    PHASE(wf0, R0, acc0);                                                         \
    TANH_PACK_STORE(acc0, W0, 0, SPAR);                                           \
    BAR();                                                                        \
    f32x4 acc1[2]; acc1[0] = biasv[0]; acc1[1] = biasv[1];                        \
    PHASER(wf1, hC, acc1);                                                        \
    PHASE(wfG, W0, acc1);                                                         \
    TANH_PACK_STORE(acc1, W1, 1, SPAR);                                           \
    BAR();                                                                        \
  } while (0)

__global__ __launch_bounds__(512, 2) void k_rnn_fused(
        const int* __restrict__ batch,
        const unsigned short* __restrict__ pre0b,
        const __hip_bfloat16* __restrict__ Whh0,
        const __hip_bfloat16* __restrict__ Wih1,
        const __hip_bfloat16* __restrict__ Whh1,
        const __hip_bfloat16* __restrict__ bih1,
        const __hip_bfloat16* __restrict__ bhh1,
        __hip_bfloat16* __restrict__ hout){
    const int l  = threadIdx.x & 63;
    const int w  = threadIdx.x >> 6;   // 0..7
    const int b0 = blockIdx.x * 16;
    const int lr = l & 15;
    const int kq = l >> 4;
    const int c0 = w * 32;
    const int cq = c0 + kq*4;

    bf16x8 wf0[2][8], wfG[2][8], wf1[2][8];
#pragma unroll
    for (int nt = 0; nt < 2; ++nt)
#pragma unroll
        for (int ks = 0; ks < 8; ++ks){
            const size_t o = (size_t)(c0 + nt*16 + lr)*NH + ks*32 + kq*8;
            wf0[nt][ks] = *reinterpret_cast<const bf16x8*>(Whh0 + o);
            wfG[nt][ks] = *reinterpret_cast<const bf16x8*>(Wih1 + o);
            wf1[nt][ks] = *reinterpret_cast<const bf16x8*>(Whh1 + o);
            asm volatile("" : "+v"(wf0[nt][ks]));
            asm volatile("" : "+v"(wfG[nt][ks]));
            asm volatile("" : "+v"(wf1[nt][ks]));
        }

    f32x4 biasv[2];
#pragma unroll
    for (int nt = 0; nt < 2; ++nt)
#pragma unroll
        for (int r = 0; r < 4; ++r){
            int c = cq + nt*16 + r;
            biasv[nt][r] = __bfloat162float(bih1[c]) + __bfloat162float(bhh1[c]);
        }

    __shared__ __align__(16) char lds_all[32768];
    char* ldsb = lds_all;
    *reinterpret_cast<uint4*>(ldsb + threadIdx.x*16)         = uint4{0,0,0,0};
    *reinterpret_cast<uint4*>(ldsb + 16384 + threadIdx.x*16) = uint4{0,0,0,0};

    const int roffb = kq*256 + lr*16;
    const int woffb = (cq >> 3)*256 + lr*16 + (cq & 7)*2;

    const int* batch_g = batch + (size_t)(b0 + lr)*NS;
    __hip_bfloat16* hop = hout + ((size_t)(b0+lr)*NS)*NH + cq;

    ushort4 xA[2], xB[2]; int iA, iB;
    {
        int j0 = batch_g[0], j1 = batch_g[1];
        const unsigned short* g0 = pre0b + (size_t)j0*NH + cq;
        const unsigned short* g1 = pre0b + (size_t)j1*NH + cq;
        xA[0] = *reinterpret_cast<const ushort4*>(g0);
        xA[1] = *reinterpret_cast<const ushort4*>(g0 + 16);
        xB[0] = *reinterpret_cast<const ushort4*>(g1);
        xB[1] = *reinterpret_cast<const ushort4*>(g1 + 16);
        iA = batch_g[2]; iB = batch_g[3];
    }
    __syncthreads();

    for (int s = 0; s < NS; s += 2){
        STEP(0,    8192, 16384, 24576, xA, iA, 0);
        STEP(8192, 0,    24576, 16384, xB, iB, 1);
        hop += 2*NH;
    }
}

// ---------------------------------------------------------------------------
// K3: output GEMM, 256-row macro-tile per WG. C[M,1000] = A[M,256]@W^T + b.
// W-frags (64 cols x 256 k) loaded ONCE into 128 pinned VGPRs, reused for
// 4 m-subtiles -> 4x less L2 W-traffic than round-12 (and grid 8192->2048).
// Fragment/D mappings identical to the round-2..12 validated k_gemm.
// ---------------------------------------------------------------------------
template<int N>
__global__ __launch_bounds__(256, 2) void k_gemm_big(
        const __hip_bfloat16* __restrict__ A,
        const __hip_bfloat16* __restrict__ W,
        const __hip_bfloat16* __restrict__ bias,
        void* __restrict__ Cout, int ldc,
        const void* __restrict__ probe){
    const bool f32out = detect_f32(probe);
    const int m0 = blockIdx.x * 256;
    const int n0 = blockIdx.y * 64;
    const int wv = threadIdx.x >> 6;
    const int l  = threadIdx.x & 63;
    const int lr = l & 15;
    const int kb = (l >> 4) * 8;

    // resident W-frags: wfr[nt][ks] = W[n0+nt*16+lr][ks*32+kb .. +8]
    bf16x8 wfr[4][8];
#pragma unroll
    for (int nt = 0; nt < 4; ++nt){
        int ncol = n0 + nt*16 + lr;
        int nc = (ncol < N) ? ncol : (N-1);
#pragma unroll
        for (int ks = 0; ks < 8; ++ks){
            wfr[nt][ks] = *reinterpret_cast<const bf16x8*>(
                W + (size_t)nc*NH + ks*32 + kb);
            asm volatile("" : "+v"(wfr[nt][ks]));
        }
    }

    float bsum[4];
#pragma unroll
    for (int nt = 0; nt < 4; ++nt){
        int ncol = n0 + nt*16 + lr;
        bsum[nt] = (ncol < N) ? __bfloat162float(bias[ncol]) : 0.f;
    }

#pragma unroll
    for (int mt = 0; mt < 4; ++mt){
        const int mrow = m0 + mt*64 + wv*16 + lr;
        bf16x8 af[8];
#pragma unroll
        for (int ks = 0; ks < 8; ++ks)
            af[ks] = *reinterpret_cast<const bf16x8*>(
                A + (size_t)mrow*NH + ks*32 + kb);
        f32x4 acc[4] = {};
#pragma unroll
        for (int ks = 0; ks < 8; ++ks){
#pragma unroll
            for (int nt = 0; nt < 4; ++nt)
                acc[nt] = __builtin_amdgcn_mfma_f32_16x16x32_bf16(
                    af[ks], wfr[nt][ks], acc[nt], 0, 0, 0);
        }
#pragma unroll
        for (int nt = 0; nt < 4; ++nt){
            int ncol = n0 + nt*16 + lr;
            if (ncol >= N) continue;
#pragma unroll
            for (int r = 0; r < 4; ++r){
                int row = m0 + mt*64 + wv*16 + (l>>4)*4 + r;
                float val = acc[nt][r] + bsum[nt];
                if (f32out) ((float*)Cout)[(size_t)row*ldc + ncol] = val;
                else        ((__hip_bfloat16*)Cout)[(size_t)row*ldc + ncol] = __float2bfloat16(val);
            }
        }
    }
}

// ---------------------------------------------------------------------------
extern "C" void kernel_launch(void* const* d_in, const int* in_sizes, int n_in,
                              void* d_out, int out_size, void* d_ws, size_t ws_size,
                              hipStream_t stream){
    const int* batch = (const int*)d_in[0];
    const void* probe = d_in[3];  // raw W_hh0 for dtype detection

    char* ws = (char*)d_ws;
    size_t off = 0;
    auto give = [&](size_t bytes)->char*{
        char* p = ws + off; off = (off + bytes + 511) & ~(size_t)511; return p;
    };
    __hip_bfloat16* cFeats = (__hip_bfloat16*)give(2*NV*NF);
    __hip_bfloat16* cWih0  = (__hip_bfloat16*)give(2*NH*NF);
    __hip_bfloat16* cWhh0  = (__hip_bfloat16*)give(2*NH*NH);
    __hip_bfloat16* cBih0  = (__hip_bfloat16*)give(2*NH);
    __hip_bfloat16* cBhh0  = (__hip_bfloat16*)give(2*NH);
    __hip_bfloat16* cWih1  = (__hip_bfloat16*)give(2*NH*NH);
    __hip_bfloat16* cWhh1  = (__hip_bfloat16*)give(2*NH*NH);
    __hip_bfloat16* cBih1  = (__hip_bfloat16*)give(2*NH);
    __hip_bfloat16* cBhh1  = (__hip_bfloat16*)give(2*NH);
    __hip_bfloat16* cWout  = (__hip_bfloat16*)give(2*NV*NH);
    __hip_bfloat16* cBout  = (__hip_bfloat16*)give(2*NV);
    __hip_bfloat16* pre0b  = (__hip_bfloat16*)give(2*NV*NH + 64);
    __hip_bfloat16* hbuf   = (__hip_bfloat16*)give(2*(size_t)NB*NS*NH);

    ConvArgs ca;
    const void* srcs[11] = { d_in[1], d_in[2], d_in[3], d_in[4], d_in[5], d_in[6],
                             d_in[7], d_in[8], d_in[9], d_in[10], d_in[11] };
    __hip_bfloat16* dsts[11] = { cFeats, cWih0, cWhh0, cBih0, cBhh0, cWih1,
                                 cWhh1, cBih1, cBhh1, cWout, cBout };
    int ns[11] = { NV*NF, NH*NF, NH*NH, NH, NH, NH*NH, NH*NH, NH, NH, NV*NH, NV };
    for (int i = 0; i < 11; ++i){ ca.src[i] = srcs[i]; ca.dst[i] = dsts[i]; ca.n[i] = ns[i]; }
    k_conv_all<<<dim3(64, 11), dim3(256), 0, stream>>>(ca, probe);

    k_pre0<<<dim3(NV), dim3(256), 0, stream>>>(cFeats, cWih0, cBih0, cBhh0, pre0b);
    k_rnn_fused<<<dim3(NB/16), dim3(512), 0, stream>>>(
        batch, (const unsigned short*)pre0b, cWhh0, cWih1, cWhh1, cBih1, cBhh1, hbuf);
    k_gemm_big<NV><<<dim3((NB*NS)/256, 16), dim3(256), 0, stream>>>(
        hbuf, cWout, cBout, d_out, NV, probe);
}